// Round 1
// baseline (807.625 us; speedup 1.0000x reference)
//
#include <hip/hip_runtime.h>

// Problem constants (LocalTopKCrossReadout)
//  B=8, Q_STEPS=16, Q_TOKENS=64 (Lq=1024), KV_STEPS=64, KV_TOKENS=64 (Lkv=4096)
//  DIM=512, WINDOW=2, TOPK=32, window width <= 5 steps = 320 kv tokens
#define NWIN 320
#define SCORE_SCALE 0.04419417382415922f  // 1/sqrt(512)

// centers = round(linspace(0, 63, 16))
__constant__ int CENTERS[16] = {0,4,8,13,17,21,25,29,34,38,42,46,50,55,59,63};

__device__ __forceinline__ float bflo(unsigned u) { return __uint_as_float(u << 16); }
__device__ __forceinline__ float bfhi(unsigned u) { return __uint_as_float(u & 0xffff0000u); }
__device__ __forceinline__ unsigned short f2bf(float x) {
  unsigned u = __float_as_uint(x);
  unsigned r = 0x7fffu + ((u >> 16) & 1u);   // round-to-nearest-even
  return (unsigned short)((u + r) >> 16);
}

// ---------------- FiLM: gb[b][0:512]=gamma, gb[b][512:1024]=beta ----------------
__global__ void film_kernel(const float* __restrict__ ctx1, const float* __restrict__ ctx2,
                            const float* __restrict__ Wc, const float* __restrict__ bc,
                            float* __restrict__ gb)
{
  const int b = blockIdx.x;       // 0..7
  const int j = threadIdx.x;      // 0..1023
  const float* c1 = ctx1 + b * 512;
  const float* c2 = ctx2 + b * 512;
  float acc = bc[j];
  #pragma unroll 4
  for (int i = 0; i < 512; ++i)
    acc = fmaf(c1[i], Wc[(size_t)i * 1024 + j], acc);
  #pragma unroll 4
  for (int i = 0; i < 512; ++i)
    acc = fmaf(c2[i], Wc[(size_t)(i + 512) * 1024 + j], acc);
  gb[b * 1024 + j] = acc;
}

// ---------------- Projection GEMM: C[M,512] = A[M,512] @ W[512,512] + bias ------
// BM=BN=128, BK=16, 256 threads, 8x8 microtile. Optional FiLM on A (Q path),
// optional bf16 output (K/V paths).
template<bool FILM, bool OUTBF16>
__global__ __launch_bounds__(256) void proj_gemm(
    const float* __restrict__ A, const float* __restrict__ W,
    const float* __restrict__ bias, const float* __restrict__ gb,
    float* __restrict__ Cf, unsigned short* __restrict__ Cb)
{
  __shared__ float As[16][132];   // k-major (transposed on store), pad 4
  __shared__ float Ws[16][132];

  const int tid  = threadIdx.x;
  const int mBlk = blockIdx.y << 7;
  const int nBlk = blockIdx.x << 7;
  const int tm   = (tid >> 4) << 3;   // 0..120
  const int tn   = (tid & 15) << 3;   // 0..120
  const int bIdx = mBlk >> 10;        // batch index (1024 q-rows per batch)

  const int ar  = tid >> 2;           // 0..63 (+64 on l=1)
  const int akq = (tid & 3) << 2;     // 0,4,8,12
  const int wr  = tid >> 5;           // 0..7  (+8 on l=1)
  const int wnq = (tid & 31) << 2;    // 0..124

  float acc[8][8] = {};

  for (int k0 = 0; k0 < 512; k0 += 16) {
    float4 g = make_float4(0.f,0.f,0.f,0.f), be = make_float4(0.f,0.f,0.f,0.f);
    if (FILM) {
      g  = *(const float4*)&gb[bIdx * 1024 + k0 + akq];
      be = *(const float4*)&gb[bIdx * 1024 + 512 + k0 + akq];
    }
    #pragma unroll
    for (int l = 0; l < 2; ++l) {
      const int r = ar + (l << 6);
      float4 a = *(const float4*)&A[(size_t)(mBlk + r) * 512 + k0 + akq];
      if (FILM) {
        a.x = fmaf(a.x, 1.f + g.x, be.x);
        a.y = fmaf(a.y, 1.f + g.y, be.y);
        a.z = fmaf(a.z, 1.f + g.z, be.z);
        a.w = fmaf(a.w, 1.f + g.w, be.w);
      }
      As[akq + 0][r] = a.x; As[akq + 1][r] = a.y;
      As[akq + 2][r] = a.z; As[akq + 3][r] = a.w;

      const int rw = wr + (l << 3);
      *(float4*)&Ws[rw][wnq] = *(const float4*)&W[(size_t)(k0 + rw) * 512 + nBlk + wnq];
    }
    __syncthreads();
    #pragma unroll 4
    for (int kk = 0; kk < 16; ++kk) {
      float a_[8], w_[8];
      *(float4*)&a_[0] = *(const float4*)&As[kk][tm];
      *(float4*)&a_[4] = *(const float4*)&As[kk][tm + 4];
      *(float4*)&w_[0] = *(const float4*)&Ws[kk][tn];
      *(float4*)&w_[4] = *(const float4*)&Ws[kk][tn + 4];
      #pragma unroll
      for (int i = 0; i < 8; ++i)
        #pragma unroll
        for (int j = 0; j < 8; ++j)
          acc[i][j] = fmaf(a_[i], w_[j], acc[i][j]);
    }
    __syncthreads();
  }

  float4 b0 = *(const float4*)&bias[nBlk + tn];
  float4 b1 = *(const float4*)&bias[nBlk + tn + 4];
  const float bia[8] = {b0.x, b0.y, b0.z, b0.w, b1.x, b1.y, b1.z, b1.w};

  #pragma unroll
  for (int i = 0; i < 8; ++i) {
    const size_t row = (size_t)(mBlk + tm + i);
    #pragma unroll
    for (int jj = 0; jj < 2; ++jj) {
      const int col = nBlk + tn + (jj << 2);
      float o0 = acc[i][jj*4+0] + bia[jj*4+0];
      float o1 = acc[i][jj*4+1] + bia[jj*4+1];
      float o2 = acc[i][jj*4+2] + bia[jj*4+2];
      float o3 = acc[i][jj*4+3] + bia[jj*4+3];
      if (OUTBF16) {
        ushort4 p;
        p.x = f2bf(o0); p.y = f2bf(o1); p.z = f2bf(o2); p.w = f2bf(o3);
        *(ushort4*)&Cb[row * 512 + col] = p;
      } else {
        float4 o = make_float4(o0, o1, o2, o3);
        *(float4*)&Cf[row * 512 + col] = o;
      }
    }
  }
}

// ---------------- Windowed scores: S[8192][320] (only first L cols valid) -------
// blockIdx.y = b*16+s (q-group of 64 rows), blockIdx.x = kv-step tile (0..4)
__global__ __launch_bounds__(256) void scores_gemm(
    const float* __restrict__ Q, const unsigned short* __restrict__ Kb,
    float* __restrict__ S)
{
  const int bs = blockIdx.y;        // 0..127
  const int s  = bs & 15;
  const int b  = bs >> 4;
  const int c  = CENTERS[s];
  const int lo = (c - 2 > 0) ? c - 2 : 0;
  const int hi = (c + 2 < 63) ? c + 2 : 63;
  if ((int)blockIdx.x > hi - lo) return;   // L=192 groups use only 3 tiles

  __shared__ float Qs[32][68];
  __shared__ float Ks[32][68];

  const int tid    = threadIdx.x;
  const int qbase  = bs << 6;                                   // q row base
  const size_t kbase = ((size_t)(b * 64 + lo + blockIdx.x)) << 6; // kv row base
  const int colBlk = blockIdx.x << 6;

  const int tm = (tid >> 4) << 2;
  const int tn = (tid & 15) << 2;

  const int qr  = tid >> 3;          // 0..31 (+32)
  const int qkq = (tid & 7) << 2;
  const int kr  = tid >> 2;          // 0..63
  const int kdq = (tid & 3) << 3;    // 0,8,16,24

  float acc[4][4] = {};

  for (int k0 = 0; k0 < 512; k0 += 32) {
    #pragma unroll
    for (int l = 0; l < 2; ++l) {
      const int r = qr + (l << 5);
      float4 a = *(const float4*)&Q[(size_t)(qbase + r) * 512 + k0 + qkq];
      Qs[qkq + 0][r] = a.x; Qs[qkq + 1][r] = a.y;
      Qs[qkq + 2][r] = a.z; Qs[qkq + 3][r] = a.w;
    }
    {
      uint4 raw = *(const uint4*)&Kb[(kbase + kr) * 512 + k0 + kdq];
      Ks[kdq + 0][kr] = bflo(raw.x); Ks[kdq + 1][kr] = bfhi(raw.x);
      Ks[kdq + 2][kr] = bflo(raw.y); Ks[kdq + 3][kr] = bfhi(raw.y);
      Ks[kdq + 4][kr] = bflo(raw.z); Ks[kdq + 5][kr] = bfhi(raw.z);
      Ks[kdq + 6][kr] = bflo(raw.w); Ks[kdq + 7][kr] = bfhi(raw.w);
    }
    __syncthreads();
    #pragma unroll 8
    for (int kk = 0; kk < 32; ++kk) {
      float4 av = *(const float4*)&Qs[kk][tm];
      float4 wv = *(const float4*)&Ks[kk][tn];
      float a_[4] = {av.x, av.y, av.z, av.w};
      float w_[4] = {wv.x, wv.y, wv.z, wv.w};
      #pragma unroll
      for (int i = 0; i < 4; ++i)
        #pragma unroll
        for (int j = 0; j < 4; ++j)
          acc[i][j] = fmaf(a_[i], w_[j], acc[i][j]);
    }
    __syncthreads();
  }

  #pragma unroll
  for (int i = 0; i < 4; ++i) {
    float4 o = make_float4(acc[i][0] * SCORE_SCALE, acc[i][1] * SCORE_SCALE,
                           acc[i][2] * SCORE_SCALE, acc[i][3] * SCORE_SCALE);
    *(float4*)&S[(size_t)(qbase + tm + i) * NWIN + colBlk + tn] = o;
  }
}

// ---------------- Top-32 + softmax + V gather (one wave per q-row) --------------
__global__ __launch_bounds__(256) void topk_pv(
    const float* __restrict__ S, const unsigned short* __restrict__ Vb,
    float* __restrict__ O)
{
  const int lane = threadIdx.x & 63;
  const int wv   = threadIdx.x >> 6;
  const int row  = (blockIdx.x << 2) + wv;     // 0..8191
  const int b    = row >> 10;
  const int s    = (row >> 6) & 15;
  const int c    = CENTERS[s];
  const int lo   = (c - 2 > 0) ? c - 2 : 0;
  const int hi   = (c + 2 < 63) ? c + 2 : 63;
  const int L    = (hi - lo + 1) << 6;         // 192 or 320
  const size_t vbase = ((size_t)b << 12) + ((size_t)lo << 6);

  const float* srow = S + (size_t)row * NWIN;
  float sc[5];
  #pragma unroll
  for (int j = 0; j < 5; ++j) {
    const int idx = lane + (j << 6);
    sc[j] = (idx < L) ? srow[idx] : -__builtin_inff();
  }

  float m = 0.f, denom = 0.f;
  float oacc[8] = {0.f,0.f,0.f,0.f,0.f,0.f,0.f,0.f};

  for (int t = 0; t < 32; ++t) {
    // local argmax over the (<=5) elements this lane owns; ties -> lower j (= lower index)
    float val = sc[0]; int jl = 0;
    #pragma unroll
    for (int j = 1; j < 5; ++j)
      if (sc[j] > val) { val = sc[j]; jl = j; }
    int gi = lane + (jl << 6);
    // wave-wide argmax with tie -> min index (matches jax.lax.top_k set semantics)
    #pragma unroll
    for (int off = 32; off > 0; off >>= 1) {
      float ov = __shfl_xor(val, off, 64);
      int   og = __shfl_xor(gi, off, 64);
      if (ov > val || (ov == val && og < gi)) { val = ov; gi = og; }
    }
    if (t == 0) m = val;                 // extraction order is descending -> t=0 is max
    const float p = __expf(val - m);
    denom += p;
    // clear the extracted element (owner lane only; static indices)
    if ((gi & 63) == lane) {
      const int jw = gi >> 6;
      #pragma unroll
      for (int j = 0; j < 5; ++j)
        if (j == jw) sc[j] = -__builtin_inff();
    }
    // accumulate p * V[selected row]; lane covers d = 2*lane + 128*e (+1)
    const unsigned short* vrow = Vb + ((vbase + (size_t)gi) << 9);
    #pragma unroll
    for (int e = 0; e < 4; ++e) {
      unsigned raw = *(const unsigned*)&vrow[(lane << 1) + (e << 7)];
      oacc[2*e]     = fmaf(p, bflo(raw), oacc[2*e]);
      oacc[2*e + 1] = fmaf(p, bfhi(raw), oacc[2*e + 1]);
    }
  }

  const float inv = 1.0f / denom;
  float* orow = O + ((size_t)row << 9);
  #pragma unroll
  for (int e = 0; e < 4; ++e) {
    float2 o2 = make_float2(oacc[2*e] * inv, oacc[2*e + 1] * inv);
    *(float2*)&orow[(lane << 1) + (e << 7)] = o2;
  }
}

// ---------------------------------------------------------------------------------
extern "C" void kernel_launch(void* const* d_in, const int* in_sizes, int n_in,
                              void* d_out, int out_size, void* d_ws, size_t ws_size,
                              hipStream_t stream)
{
  (void)in_sizes; (void)n_in; (void)out_size; (void)ws_size;

  const float* query  = (const float*)d_in[0];
  const float* source = (const float*)d_in[1];
  const float* ctx1   = (const float*)d_in[2];
  const float* ctx2   = (const float*)d_in[3];
  const float* Wq     = (const float*)d_in[4];
  const float* bq     = (const float*)d_in[5];
  const float* Wk     = (const float*)d_in[6];
  const float* bk     = (const float*)d_in[7];
  const float* Wv     = (const float*)d_in[8];
  const float* bv     = (const float*)d_in[9];
  const float* Wo     = (const float*)d_in[10];
  const float* bo     = (const float*)d_in[11];
  const float* Wc     = (const float*)d_in[12];
  const float* bc     = (const float*)d_in[13];
  float* out = (float*)d_out;

  // Workspace layout (total 94,404,608 B):
  //  q / ctxout (aliased): 8192*512*4  = 16,777,216
  //  k (bf16):             32768*512*2 = 33,554,432
  //  v (bf16):             32768*512*2 = 33,554,432
  //  S (scores f32):       8192*320*4  = 10,485,760
  //  gb (gamma|beta f32):  8*1024*4    = 32,768
  char* ws = (char*)d_ws;
  float*          q  = (float*)(ws);
  unsigned short* k  = (unsigned short*)(ws + 16777216);
  unsigned short* v  = (unsigned short*)(ws + 50331648);
  float*          S  = (float*)(ws + 83886080);
  float*          gb = (float*)(ws + 94371840);

  film_kernel<<<8, 1024, 0, stream>>>(ctx1, ctx2, Wc, bc, gb);
  // Q = FiLM(query) @ Wq + bq   (f32 out)
  proj_gemm<true,  false><<<dim3(4, 64),  256, 0, stream>>>(query,  Wq, bq, gb, q,  nullptr);
  // K = source @ Wk + bk        (bf16 out)
  proj_gemm<false, true ><<<dim3(4, 256), 256, 0, stream>>>(source, Wk, bk, gb, nullptr, k);
  // V = source @ Wv + bv        (bf16 out)
  proj_gemm<false, true ><<<dim3(4, 256), 256, 0, stream>>>(source, Wv, bv, gb, nullptr, v);
  // windowed scores
  scores_gemm<<<dim3(5, 128), 256, 0, stream>>>(q, k, S);
  // top-32 + softmax + PV  (writes ctxout into q's buffer; q is dead after scores)
  topk_pv<<<2048, 256, 0, stream>>>(S, v, q);
  // out = ctxout @ Wo + bo
  proj_gemm<false, false><<<dim3(4, 64),  256, 0, stream>>>(q, Wo, bo, gb, out, nullptr);
}

// Round 3
// 302.902 us; speedup vs baseline: 2.6663x; 2.6663x over previous
//
#include <hip/hip_runtime.h>

// LocalTopKCrossReadout: B=8, Lq=1024 (16 steps x 64), Lkv=4096 (64 x 64),
// DIM=512, WINDOW=2 (<=5 steps = 320 cols), TOPK=32.
#define NWIN 320
#define SCORE_SCALE 0.04419417382415922f  // 1/sqrt(512)

__constant__ int CENTERS[16] = {0,4,8,13,17,21,25,29,34,38,42,46,50,55,59,63};

typedef __attribute__((ext_vector_type(8))) short v8s;   // 8 bf16
typedef __attribute__((ext_vector_type(4))) float v4f;   // 4 f32 acc

__device__ __forceinline__ float bflo(unsigned u) { return __uint_as_float(u << 16); }
__device__ __forceinline__ float bfhi(unsigned u) { return __uint_as_float(u & 0xffff0000u); }
__device__ __forceinline__ float bf2f(unsigned short h) { return __uint_as_float(((unsigned)h) << 16); }
__device__ __forceinline__ unsigned short f2bf(float x) {
  unsigned u = __float_as_uint(x);
  unsigned r = 0x7fffu + ((u >> 16) & 1u);   // RNE
  return (unsigned short)((u + r) >> 16);
}

// ---- T64 tile: 64 rows x 32 k bf16 in 4096 B, XOR-swizzled for conflict-free b128 ----
__device__ __forceinline__ int t64_off(int r, int k) {
  return ((r & 31) << 7) + (((((r >> 5) << 2) | (k >> 3)) ^ (r & 7)) << 4) + ((k & 7) << 1);
}
__device__ __forceinline__ int frag_off(int r, int g) {
  return ((r & 31) << 7) + (((((r >> 5) << 2) | g) ^ (r & 7)) << 4);
}

__device__ __forceinline__ void gload_lds16(const void* g, void* l) {
  __builtin_amdgcn_global_load_lds((const __attribute__((address_space(1))) unsigned int*)g,
                                   (__attribute__((address_space(3))) unsigned int*)l, 16, 0, 0);
}

// pack 8 f32 -> 8 bf16 (hi part, or lo residual part)
__device__ __forceinline__ uint4 cvt8(float4 a, float4 b, bool lom) {
  float v[8] = {a.x, a.y, a.z, a.w, b.x, b.y, b.z, b.w};
  unsigned short h[8];
  #pragma unroll
  for (int e = 0; e < 8; ++e) {
    unsigned short hi = f2bf(v[e]);
    h[e] = lom ? f2bf(v[e] - bf2f(hi)) : hi;
  }
  uint4 u;
  u.x = (unsigned)h[0] | ((unsigned)h[1] << 16);
  u.y = (unsigned)h[2] | ((unsigned)h[3] << 16);
  u.z = (unsigned)h[4] | ((unsigned)h[5] << 16);
  u.w = (unsigned)h[6] | ((unsigned)h[7] << 16);
  return u;
}

// ---------------- FiLM (two-stage, parallel over k-slices) ----------------
__global__ void film_part(const float* __restrict__ ctx1, const float* __restrict__ ctx2,
                          const float* __restrict__ Wc, float* __restrict__ part)
{
  const int b = blockIdx.y, sl = blockIdx.x, j = threadIdx.x;
  const int i0 = sl * 128;
  float acc = 0.f;
  #pragma unroll 4
  for (int t = 0; t < 128; ++t) {
    const int i = i0 + t;
    const float f = (i < 512) ? ctx1[b * 512 + i] : ctx2[b * 512 + i - 512];
    acc = fmaf(f, Wc[(size_t)i * 1024 + j], acc);
  }
  part[(b * 8 + sl) * 1024 + j] = acc;
}

__global__ void film_reduce(const float* __restrict__ part, const float* __restrict__ bc,
                            float* __restrict__ gb)
{
  const int b = blockIdx.x, j = threadIdx.x;
  float acc = bc[j];
  #pragma unroll
  for (int sl = 0; sl < 8; ++sl) acc += part[(b * 8 + sl) * 1024 + j];
  gb[b * 1024 + j] = acc;
}

// ---------------- u = Wk . bq  (512-dim) ----------------
__global__ void u_kernel(const float* __restrict__ Wk, const float* __restrict__ bq,
                         float* __restrict__ u)
{
  const int d = blockIdx.x, lane = threadIdx.x;
  float4 a0 = *(const float4*)&Wk[(size_t)d * 512 + lane * 8];
  float4 a1 = *(const float4*)&Wk[(size_t)d * 512 + lane * 8 + 4];
  float4 c0 = *(const float4*)&bq[lane * 8];
  float4 c1 = *(const float4*)&bq[lane * 8 + 4];
  float s = a0.x*c0.x + a0.y*c0.y + a0.z*c0.z + a0.w*c0.w
          + a1.x*c1.x + a1.y*c1.y + a1.z*c1.z + a1.w*c1.w;
  #pragma unroll
  for (int off = 32; off > 0; off >>= 1) s += __shfl_xor(s, off, 64);
  if (lane == 0) u[d] = s;
}

// ---------------- r[j] = source_j . u  (32768 rows) ----------------
__global__ __launch_bounds__(256) void r_kernel(const float* __restrict__ SRC,
    const float* __restrict__ u, float* __restrict__ Rv)
{
  const int j = blockIdx.x * 4 + (threadIdx.x >> 6);
  const int lane = threadIdx.x & 63;
  float4 u0 = *(const float4*)&u[lane * 8];
  float4 u1 = *(const float4*)&u[lane * 8 + 4];
  float4 s0 = *(const float4*)&SRC[(size_t)j * 512 + lane * 8];
  float4 s1 = *(const float4*)&SRC[(size_t)j * 512 + lane * 8 + 4];
  float s = s0.x*u0.x + s0.y*u0.y + s0.z*u0.z + s0.w*u0.w
          + s1.x*u1.x + s1.y*u1.y + s1.z*u1.z + s1.w*u1.w;
  #pragma unroll
  for (int off = 32; off > 0; off >>= 1) s += __shfl_xor(s, off, 64);
  if (lane == 0) Rv[j] = s;
}

// ---------------- G = Wq @ Wk^T  (f32 exact), epilogue -> hi/lo T64 tiles ----------------
__global__ __launch_bounds__(256) void gmat_kernel(
    const float* __restrict__ Wq, const float* __restrict__ Wk,
    unsigned short* __restrict__ Gt)
{
  __shared__ float Qs[32][68];
  __shared__ float Ks[32][68];
  const int tid = threadIdx.x;
  const int ib = blockIdx.y << 6, jb = blockIdx.x << 6;
  const int tm = (tid >> 4) << 2, tn = (tid & 15) << 2;
  const int qr = tid >> 3, qk = (tid & 7) << 2;
  float acc[4][4] = {};
  for (int k0 = 0; k0 < 512; k0 += 32) {
    #pragma unroll
    for (int l = 0; l < 2; ++l) {
      const int r = qr + (l << 5);
      float4 a = *(const float4*)&Wq[(size_t)(ib + r) * 512 + k0 + qk];
      Qs[qk+0][r] = a.x; Qs[qk+1][r] = a.y; Qs[qk+2][r] = a.z; Qs[qk+3][r] = a.w;
      float4 w = *(const float4*)&Wk[(size_t)(jb + r) * 512 + k0 + qk];
      Ks[qk+0][r] = w.x; Ks[qk+1][r] = w.y; Ks[qk+2][r] = w.z; Ks[qk+3][r] = w.w;
    }
    __syncthreads();
    #pragma unroll 8
    for (int kk = 0; kk < 32; ++kk) {
      float a_[4], b_[4];
      *(float4*)&a_[0] = *(const float4*)&Qs[kk][tm];
      *(float4*)&b_[0] = *(const float4*)&Ks[kk][tn];
      #pragma unroll
      for (int i = 0; i < 4; ++i)
        #pragma unroll
        for (int j = 0; j < 4; ++j)
          acc[i][j] = fmaf(a_[i], b_[j], acc[i][j]);
    }
    __syncthreads();
  }
  #pragma unroll
  for (int i = 0; i < 4; ++i) {
    #pragma unroll
    for (int j = 0; j < 4; ++j) {
      const int gi = ib + tm + i;   // k-dim of qg GEMM
      const int gj = jb + tn + j;   // n-dim
      const float v = acc[i][j];
      const unsigned short hi = f2bf(v);
      const unsigned short lo = f2bf(v - bf2f(hi));
      const int toff = t64_off(gj & 63, gi & 31);
      *(unsigned short*)((char*)Gt + ((size_t)((gi >> 5) * 8 + (gj >> 6)) << 12) + toff) = hi;
      *(unsigned short*)((char*)Gt + ((size_t)(((gi >> 5) + 16) * 8 + (gj >> 6)) << 12) + toff) = lo;
    }
  }
}

// ---------------- Wv/Wo -> T64 hi tiles (W^T layout) ----------------
__global__ __launch_bounds__(256) void wconv_kernel(
    const float* __restrict__ Wv, const float* __restrict__ Wo,
    unsigned short* __restrict__ Wvt, unsigned short* __restrict__ Wot)
{
  __shared__ char img[32768];
  const int ktile = blockIdx.x;  // 0..15
  const int mat   = blockIdx.y;  // 0:Wv 1:Wo
  const float* W = mat ? Wo : Wv;
  unsigned short* Dt = mat ? Wot : Wvt;
  const int tid = threadIdx.x;
  const int k  = tid >> 3;       // 0..31
  const int nt = tid & 7;        // ntile 0..7
  #pragma unroll
  for (int e4 = 0; e4 < 16; ++e4) {
    float4 w = *(const float4*)&W[(size_t)(ktile * 32 + k) * 512 + nt * 64 + e4 * 4];
    float vv[4] = {w.x, w.y, w.z, w.w};
    #pragma unroll
    for (int c = 0; c < 4; ++c) {
      const int n = e4 * 4 + c;
      *(unsigned short*)(img + nt * 4096 + t64_off(n, k)) = f2bf(vv[c]);
    }
  }
  __syncthreads();
  const uint4* src = (const uint4*)img;
  uint4* dst = (uint4*)((char*)Dt + (size_t)ktile * 32768);
  for (int i = tid; i < 2048; i += 256) dst[i] = src[i];
}

// ---------------- MFMA projection: C[M,512] = A[M,512] @ Bt(+bias) ----------------
// BM=64, BN=256, 256 thr (4 waves 2x2; wave tile 32x128). A: f32 reg-staged ->
// bf16 hi/lo. Bt: pre-tiled T64, staged via global_load_lds. SPLIT: K'=1536
// 3-product hi/lo schedule. 2-barrier-per-step (m97-proven epoch structure):
// every LDS byte alternates strict write-epoch / read-epoch separated by barriers.
template<bool FILM, bool BIAS, bool OUTBF16, bool SPLIT>
__global__ __launch_bounds__(256) void proj_mfma(
    const float* __restrict__ A, const unsigned short* __restrict__ Bt,
    const float* __restrict__ bias, const float* __restrict__ gb,
    float* __restrict__ Cf, unsigned short* __restrict__ Cb)
{
  constexpr int KT = SPLIT ? 48 : 16;
  __shared__ char smem[4096 + 16384];   // A tile | B tile (single-buffered)
  char* const LA = smem;
  char* const LB = smem + 4096;

  const int tid  = threadIdx.x;
  const int lane = tid & 63, l15 = lane & 15, g = lane >> 4;
  const int wave = tid >> 6, wm = wave >> 1, wn = wave & 1;
  const int mBlk = blockIdx.y;
  const int nBlk = blockIdx.x;

  const int sr = tid >> 2;   // 0..63
  const int sq = tid & 3;    // k-octet
  const size_t arow = (size_t)(mBlk * 64 + sr) * 512 + sq * 8;
  const int gbbase = FILM ? ((((mBlk * 64) >> 10) * 1024) + sq * 8) : 0;
  const int awoff = t64_off(sr, sq * 8);

  int aoff[2], boff[8];
  #pragma unroll
  for (int fm = 0; fm < 2; ++fm) aoff[fm] = frag_off(wm * 32 + fm * 16 + l15, g);
  #pragma unroll
  for (int fn = 0; fn < 8; ++fn) {
    const int n = wn * 128 + fn * 16 + l15;
    boff[fn] = ((n >> 6) << 12) + frag_off(n & 63, g);
  }

  v4f acc[2][8];
  #pragma unroll
  for (int fm = 0; fm < 2; ++fm)
    #pragma unroll
    for (int fn = 0; fn < 8; ++fn) acc[fm][fn] = (v4f){0.f, 0.f, 0.f, 0.f};

  for (int tk = 0; tk < KT; ++tk) {
    const int  kd  = (SPLIT ? (tk & 15) : tk) * 32;
    const bool lom = SPLIT && ((tk >> 4) == 1);
    const int  pb  = SPLIT ? ((tk < 32) ? (tk & 15) : (tk - 16)) : tk;

    {  // B: 16 KB identity-copy (tiles are the LDS image)
      const char* gs = (const char*)Bt + ((size_t)(pb * 8 + nBlk * 4) << 12) + (size_t)tid * 16;
      char* ld = LB + (wave << 10);
      #pragma unroll
      for (int i = 0; i < 4; ++i) gload_lds16(gs + i * 4096, ld + i * 4096);
    }
    {  // A: f32 -> bf16 (hi or lo), swizzled ds_write_b128
      float4 x0 = *(const float4*)&A[arow + kd];
      float4 x1 = *(const float4*)&A[arow + kd + 4];
      if (FILM) {
        float4 g0 = *(const float4*)&gb[gbbase + kd];
        float4 g1 = *(const float4*)&gb[gbbase + kd + 4];
        float4 b0 = *(const float4*)&gb[gbbase + 512 + kd];
        float4 b1 = *(const float4*)&gb[gbbase + 512 + kd + 4];
        x0.x = fmaf(x0.x, 1.f + g0.x, b0.x); x0.y = fmaf(x0.y, 1.f + g0.y, b0.y);
        x0.z = fmaf(x0.z, 1.f + g0.z, b0.z); x0.w = fmaf(x0.w, 1.f + g0.w, b0.w);
        x1.x = fmaf(x1.x, 1.f + g1.x, b1.x); x1.y = fmaf(x1.y, 1.f + g1.y, b1.y);
        x1.z = fmaf(x1.z, 1.f + g1.z, b1.z); x1.w = fmaf(x1.w, 1.f + g1.w, b1.w);
      }
      *(uint4*)(LA + awoff) = cvt8(x0, x1, lom);
    }
    __syncthreads();   // write-epoch -> read-epoch (drains vmcnt+lgkmcnt)
    const v8s a0 = *(const v8s*)(LA + aoff[0]);
    const v8s a1 = *(const v8s*)(LA + aoff[1]);
    #pragma unroll
    for (int fn = 0; fn < 8; ++fn) {
      const v8s bb = *(const v8s*)(LB + boff[fn]);
      acc[0][fn] = __builtin_amdgcn_mfma_f32_16x16x32_bf16(a0, bb, acc[0][fn], 0, 0, 0);
      acc[1][fn] = __builtin_amdgcn_mfma_f32_16x16x32_bf16(a1, bb, acc[1][fn], 0, 0, 0);
    }
    __syncthreads();   // read-epoch -> next write-epoch (closes WAR window)
  }

  #pragma unroll
  for (int fn = 0; fn < 8; ++fn) {
    const int col = nBlk * 256 + wn * 128 + fn * 16 + l15;
    const float bv = BIAS ? bias[col] : 0.f;
    #pragma unroll
    for (int fm = 0; fm < 2; ++fm) {
      const int r0 = mBlk * 64 + wm * 32 + fm * 16 + g * 4;
      #pragma unroll
      for (int k = 0; k < 4; ++k) {
        const float v = acc[fm][fn][k] + bv;
        if (OUTBF16) Cb[(size_t)(r0 + k) * 512 + col] = f2bf(v);
        else         Cf[(size_t)(r0 + k) * 512 + col] = v;
      }
    }
  }
}

// ---------------- Windowed scores via MFMA (split hi/lo, K'=1536) ----------------
// S = (qg . src^T + r_j) * scale ; block = (kv-step tile, q-group). 2-barrier epochs.
__global__ __launch_bounds__(256) void scores_mfma(
    const float* __restrict__ QG, const float* __restrict__ SRC,
    const float* __restrict__ Rv, float* __restrict__ S)
{
  const int bs = blockIdx.y;
  const int s = bs & 15, b = bs >> 4;
  const int c  = CENTERS[s];
  const int lo = (c - 2 > 0) ? c - 2 : 0;
  const int hi = (c + 2 < 63) ? c + 2 : 63;
  if ((int)blockIdx.x > hi - lo) return;

  __shared__ char smem[8192];   // A 4K | B 4K (single-buffered)
  char* const LA = smem;
  char* const LB = smem + 4096;

  const int tid = threadIdx.x;
  const int lane = tid & 63, l15 = lane & 15, g = lane >> 4;
  const int wave = tid >> 6, wm = wave >> 1, wn = wave & 1;
  const int qbase  = bs << 6;
  const int kvrow0 = (b << 12) + ((lo + (int)blockIdx.x) << 6);
  const int sr = tid >> 2, sq = tid & 3;
  const size_t qrow = (size_t)(qbase + sr) * 512 + sq * 8;
  const size_t krow = (size_t)(kvrow0 + sr) * 512 + sq * 8;
  const int awoff = t64_off(sr, sq * 8);

  int aoff[2], boff[2];
  #pragma unroll
  for (int f = 0; f < 2; ++f) {
    aoff[f] = frag_off(wm * 32 + f * 16 + l15, g);
    boff[f] = frag_off(wn * 32 + f * 16 + l15, g);
  }

  v4f acc[2][2];
  #pragma unroll
  for (int i = 0; i < 2; ++i)
    #pragma unroll
    for (int j = 0; j < 2; ++j) acc[i][j] = (v4f){0.f, 0.f, 0.f, 0.f};

  for (int tk = 0; tk < 48; ++tk) {
    const int  kd  = (tk & 15) * 32;
    const bool alo = (tk >> 4) == 1;
    const bool blo = tk >= 32;
    {
      float4 x0 = *(const float4*)&QG[qrow + kd];
      float4 x1 = *(const float4*)&QG[qrow + kd + 4];
      *(uint4*)(LA + awoff) = cvt8(x0, x1, alo);
      float4 y0 = *(const float4*)&SRC[krow + kd];
      float4 y1 = *(const float4*)&SRC[krow + kd + 4];
      *(uint4*)(LB + awoff) = cvt8(y0, y1, blo);
    }
    __syncthreads();   // write-epoch -> read-epoch
    const v8s a0 = *(const v8s*)(LA + aoff[0]);
    const v8s a1 = *(const v8s*)(LA + aoff[1]);
    const v8s b0 = *(const v8s*)(LB + boff[0]);
    const v8s b1 = *(const v8s*)(LB + boff[1]);
    acc[0][0] = __builtin_amdgcn_mfma_f32_16x16x32_bf16(a0, b0, acc[0][0], 0, 0, 0);
    acc[0][1] = __builtin_amdgcn_mfma_f32_16x16x32_bf16(a0, b1, acc[0][1], 0, 0, 0);
    acc[1][0] = __builtin_amdgcn_mfma_f32_16x16x32_bf16(a1, b0, acc[1][0], 0, 0, 0);
    acc[1][1] = __builtin_amdgcn_mfma_f32_16x16x32_bf16(a1, b1, acc[1][1], 0, 0, 0);
    __syncthreads();   // read-epoch -> next write-epoch
  }

  #pragma unroll
  for (int fn = 0; fn < 2; ++fn) {
    const int cl = wn * 32 + fn * 16 + l15;
    const float rv = Rv[kvrow0 + cl];
    const int colS = ((int)blockIdx.x << 6) + cl;
    #pragma unroll
    for (int fm = 0; fm < 2; ++fm) {
      const int r0 = qbase + wm * 32 + fm * 16 + g * 4;
      #pragma unroll
      for (int k = 0; k < 4; ++k)
        S[(size_t)(r0 + k) * NWIN + colS] = (acc[fm][fn][k] + rv) * SCORE_SCALE;
    }
  }
}

// ---------------- Top-32 + softmax + V gather (one wave per q-row) ----------------
__global__ __launch_bounds__(256) void topk_pv(
    const float* __restrict__ S, const unsigned short* __restrict__ Vb,
    float* __restrict__ O)
{
  const int lane = threadIdx.x & 63;
  const int wv   = threadIdx.x >> 6;
  const int row  = (blockIdx.x << 2) + wv;
  const int b    = row >> 10;
  const int s    = (row >> 6) & 15;
  const int c    = CENTERS[s];
  const int lo   = (c - 2 > 0) ? c - 2 : 0;
  const int hi   = (c + 2 < 63) ? c + 2 : 63;
  const int L    = (hi - lo + 1) << 6;
  const size_t vbase = ((size_t)b << 12) + ((size_t)lo << 6);

  const float* srow = S + (size_t)row * NWIN;
  float sc[5];
  #pragma unroll
  for (int j = 0; j < 5; ++j) {
    const int idx = lane + (j << 6);
    sc[j] = (idx < L) ? srow[idx] : -__builtin_inff();
  }

  float m = 0.f, denom = 0.f;
  float oacc[8] = {0.f,0.f,0.f,0.f,0.f,0.f,0.f,0.f};

  for (int t = 0; t < 32; ++t) {
    float val = sc[0]; int jl = 0;
    #pragma unroll
    for (int j = 1; j < 5; ++j)
      if (sc[j] > val) { val = sc[j]; jl = j; }
    int gi = lane + (jl << 6);
    #pragma unroll
    for (int off = 32; off > 0; off >>= 1) {
      float ov = __shfl_xor(val, off, 64);
      int   og = __shfl_xor(gi, off, 64);
      if (ov > val || (ov == val && og < gi)) { val = ov; gi = og; }
    }
    if (t == 0) m = val;
    const float p = __expf(val - m);
    denom += p;
    if ((gi & 63) == lane) {
      const int jw = gi >> 6;
      #pragma unroll
      for (int j = 0; j < 5; ++j)
        if (j == jw) sc[j] = -__builtin_inff();
    }
    const unsigned short* vrow = Vb + ((vbase + (size_t)gi) << 9);
    #pragma unroll
    for (int e = 0; e < 4; ++e) {
      unsigned raw = *(const unsigned*)&vrow[(lane << 1) + (e << 7)];
      oacc[2*e]     = fmaf(p, bflo(raw), oacc[2*e]);
      oacc[2*e + 1] = fmaf(p, bfhi(raw), oacc[2*e + 1]);
    }
  }

  const float inv = 1.0f / denom;
  float* orow = O + ((size_t)row << 9);
  #pragma unroll
  for (int e = 0; e < 4; ++e) {
    float2 o2 = make_float2(oacc[2*e] * inv, oacc[2*e + 1] * inv);
    *(float2*)&orow[(lane << 1) + (e << 7)] = o2;
  }
}

// ---------------------------------------------------------------------------------
extern "C" void kernel_launch(void* const* d_in, const int* in_sizes, int n_in,
                              void* d_out, int out_size, void* d_ws, size_t ws_size,
                              hipStream_t stream)
{
  (void)in_sizes; (void)n_in; (void)out_size; (void)ws_size;

  const float* query  = (const float*)d_in[0];
  const float* source = (const float*)d_in[1];
  const float* ctx1   = (const float*)d_in[2];
  const float* ctx2   = (const float*)d_in[3];
  const float* Wq     = (const float*)d_in[4];
  const float* bq     = (const float*)d_in[5];
  const float* Wk     = (const float*)d_in[6];
  // bk (d_in[7]) only contributes row-constant score terms -> provably droppable
  const float* Wv     = (const float*)d_in[8];
  const float* bv     = (const float*)d_in[9];
  const float* Wo     = (const float*)d_in[10];
  const float* bo     = (const float*)d_in[11];
  const float* Wc     = (const float*)d_in[12];
  const float* bc     = (const float*)d_in[13];
  float* out = (float*)d_out;

  // Workspace (80,119,808 B total; round 1 proved >= 94.4 MB available):
  char* ws = (char*)d_ws;
  float*          qg   = (float*)(ws);                       // 16,777,216
  unsigned short* v    = (unsigned short*)(ws + 16777216);   // 33,554,432
  float*          S    = (float*)(ws + 50331648);            // 10,485,760
  float*          ctx  = (float*)(ws + 60817408);            // 16,777,216
  unsigned short* Gt   = (unsigned short*)(ws + 77594624);   //  1,048,576
  unsigned short* Wvt  = (unsigned short*)(ws + 78643200);   //    524,288
  unsigned short* Wot  = (unsigned short*)(ws + 79167488);   //    524,288
  float*          gb   = (float*)(ws + 79691776);            //     32,768
  float*          part = (float*)(ws + 79724544);            //    262,144
  float*          u    = (float*)(ws + 79986688);            //      2,048
  float*          Rv   = (float*)(ws + 79988736);            //    131,072

  film_part  <<<dim3(8, 8), 1024, 0, stream>>>(ctx1, ctx2, Wc, part);
  film_reduce<<<8, 1024, 0, stream>>>(part, bc, gb);
  u_kernel   <<<512, 64, 0, stream>>>(Wk, bq, u);
  r_kernel   <<<8192, 256, 0, stream>>>(source, u, Rv);
  gmat_kernel<<<dim3(8, 8), 256, 0, stream>>>(Wq, Wk, Gt);
  wconv_kernel<<<dim3(16, 2), 256, 0, stream>>>(Wv, Wo, Wvt, Wot);

  // qg = FiLM(query) @ G   (split hi/lo, no bias)
  proj_mfma<true,  false, false, true ><<<dim3(2, 128), 256, 0, stream>>>(query,  Gt,  nullptr, gb, qg, nullptr);
  // v = source @ Wv + bv   (bf16 out)
  proj_mfma<false, true,  true,  false><<<dim3(2, 512), 256, 0, stream>>>(source, Wvt, bv, nullptr, nullptr, v);
  // windowed scores (split hi/lo on both operands) + bias term r_j
  scores_mfma<<<dim3(5, 128), 256, 0, stream>>>(qg, source, Rv, S);
  // top-32 + softmax + PV
  topk_pv<<<2048, 256, 0, stream>>>(S, v, ctx);
  // out = ctx @ Wo + bo
  proj_mfma<false, true,  false, false><<<dim3(2, 128), 256, 0, stream>>>(ctx, Wot, bo, nullptr, out, nullptr);
}

// Round 4
// 215.858 us; speedup vs baseline: 3.7415x; 1.4032x over previous
//
#include <hip/hip_runtime.h>

// LocalTopKCrossReadout: B=8, Lq=1024 (16 steps x 64), Lkv=4096 (64 x 64),
// DIM=512, WINDOW=2 (<=5 steps = 320 cols), TOPK=32.
#define NWIN 320
#define SCORE_SCALE 0.04419417382415922f  // 1/sqrt(512)

__constant__ int CENTERS[16] = {0,4,8,13,17,21,25,29,34,38,42,46,50,55,59,63};

typedef __attribute__((ext_vector_type(8))) short v8s;   // 8 bf16
typedef __attribute__((ext_vector_type(4))) float v4f;   // 4 f32 acc

__device__ __forceinline__ float bflo(unsigned u) { return __uint_as_float(u << 16); }
__device__ __forceinline__ float bfhi(unsigned u) { return __uint_as_float(u & 0xffff0000u); }
__device__ __forceinline__ float bf2f(unsigned short h) { return __uint_as_float(((unsigned)h) << 16); }
__device__ __forceinline__ unsigned short f2bf(float x) {
  unsigned u = __float_as_uint(x);
  unsigned r = 0x7fffu + ((u >> 16) & 1u);   // RNE
  return (unsigned short)((u + r) >> 16);
}

// ---- T64 tile: 64 rows x 32 k bf16 in 4096 B, XOR-swizzled for conflict-free b128 ----
__device__ __forceinline__ int t64_off(int r, int k) {
  return ((r & 31) << 7) + (((((r >> 5) << 2) | (k >> 3)) ^ (r & 7)) << 4) + ((k & 7) << 1);
}
__device__ __forceinline__ int frag_off(int r, int g) {
  return ((r & 31) << 7) + (((((r >> 5) << 2) | g) ^ (r & 7)) << 4);
}

__device__ __forceinline__ void gload_lds16(const void* g, void* l) {
  __builtin_amdgcn_global_load_lds((const __attribute__((address_space(1))) unsigned int*)g,
                                   (__attribute__((address_space(3))) unsigned int*)l, 16, 0, 0);
}

// pack 8 f32 -> hi-bf16 plane AND lo-residual plane in one shot
__device__ __forceinline__ void cvt8pair(float4 a, float4 b, uint4& hi4, uint4& lo4) {
  float v[8] = {a.x, a.y, a.z, a.w, b.x, b.y, b.z, b.w};
  unsigned short h[8], l[8];
  #pragma unroll
  for (int e = 0; e < 8; ++e) {
    h[e] = f2bf(v[e]);
    l[e] = f2bf(v[e] - bf2f(h[e]));
  }
  hi4.x = (unsigned)h[0] | ((unsigned)h[1] << 16);
  hi4.y = (unsigned)h[2] | ((unsigned)h[3] << 16);
  hi4.z = (unsigned)h[4] | ((unsigned)h[5] << 16);
  hi4.w = (unsigned)h[6] | ((unsigned)h[7] << 16);
  lo4.x = (unsigned)l[0] | ((unsigned)l[1] << 16);
  lo4.y = (unsigned)l[2] | ((unsigned)l[3] << 16);
  lo4.z = (unsigned)l[4] | ((unsigned)l[5] << 16);
  lo4.w = (unsigned)l[6] | ((unsigned)l[7] << 16);
}

__device__ __forceinline__ uint2 cvt4(float4 a) {
  uint2 r;
  r.x = (unsigned)f2bf(a.x) | ((unsigned)f2bf(a.y) << 16);
  r.y = (unsigned)f2bf(a.z) | ((unsigned)f2bf(a.w) << 16);
  return r;
}

// ---------------- FiLM (two-stage, parallel over k-slices) ----------------
__global__ void film_part(const float* __restrict__ ctx1, const float* __restrict__ ctx2,
                          const float* __restrict__ Wc, float* __restrict__ part)
{
  const int b = blockIdx.y, sl = blockIdx.x, j = threadIdx.x;
  const int i0 = sl * 128;
  float acc = 0.f;
  #pragma unroll 4
  for (int t = 0; t < 128; ++t) {
    const int i = i0 + t;
    const float f = (i < 512) ? ctx1[b * 512 + i] : ctx2[b * 512 + i - 512];
    acc = fmaf(f, Wc[(size_t)i * 1024 + j], acc);
  }
  part[(b * 8 + sl) * 1024 + j] = acc;
}

__global__ void film_reduce(const float* __restrict__ part, const float* __restrict__ bc,
                            float* __restrict__ gb)
{
  const int b = blockIdx.x, j = threadIdx.x;
  float acc = bc[j];
  #pragma unroll
  for (int sl = 0; sl < 8; ++sl) acc += part[(b * 8 + sl) * 1024 + j];
  gb[b * 1024 + j] = acc;
}

// ---------------- u = (Wk . bq) * scale  (512-dim) ----------------
__global__ void u_kernel(const float* __restrict__ Wk, const float* __restrict__ bq,
                         float* __restrict__ u)
{
  const int d = blockIdx.x, lane = threadIdx.x;
  float4 a0 = *(const float4*)&Wk[(size_t)d * 512 + lane * 8];
  float4 a1 = *(const float4*)&Wk[(size_t)d * 512 + lane * 8 + 4];
  float4 c0 = *(const float4*)&bq[lane * 8];
  float4 c1 = *(const float4*)&bq[lane * 8 + 4];
  float s = a0.x*c0.x + a0.y*c0.y + a0.z*c0.z + a0.w*c0.w
          + a1.x*c1.x + a1.y*c1.y + a1.z*c1.z + a1.w*c1.w;
  #pragma unroll
  for (int off = 32; off > 0; off >>= 1) s += __shfl_xor(s, off, 64);
  if (lane == 0) u[d] = s * SCORE_SCALE;
}

// ---------------- G = (Wq @ Wk^T)*scale (f32 exact) -> hi/lo T64 tiles ----------------
__global__ __launch_bounds__(256) void gmat_kernel(
    const float* __restrict__ Wq, const float* __restrict__ Wk,
    unsigned short* __restrict__ Gt)
{
  __shared__ float Qs[32][68];
  __shared__ float Ks[32][68];
  const int tid = threadIdx.x;
  const int ib = blockIdx.y << 6, jb = blockIdx.x << 6;
  const int tm = (tid >> 4) << 2, tn = (tid & 15) << 2;
  const int qr = tid >> 3, qk = (tid & 7) << 2;
  float acc[4][4] = {};
  for (int k0 = 0; k0 < 512; k0 += 32) {
    #pragma unroll
    for (int l = 0; l < 2; ++l) {
      const int r = qr + (l << 5);
      float4 a = *(const float4*)&Wq[(size_t)(ib + r) * 512 + k0 + qk];
      Qs[qk+0][r] = a.x; Qs[qk+1][r] = a.y; Qs[qk+2][r] = a.z; Qs[qk+3][r] = a.w;
      float4 w = *(const float4*)&Wk[(size_t)(jb + r) * 512 + k0 + qk];
      Ks[qk+0][r] = w.x; Ks[qk+1][r] = w.y; Ks[qk+2][r] = w.z; Ks[qk+3][r] = w.w;
    }
    __syncthreads();
    #pragma unroll 8
    for (int kk = 0; kk < 32; ++kk) {
      float a_[4], b_[4];
      *(float4*)&a_[0] = *(const float4*)&Qs[kk][tm];
      *(float4*)&b_[0] = *(const float4*)&Ks[kk][tn];
      #pragma unroll
      for (int i = 0; i < 4; ++i)
        #pragma unroll
        for (int j = 0; j < 4; ++j)
          acc[i][j] = fmaf(a_[i], b_[j], acc[i][j]);
    }
    __syncthreads();
  }
  #pragma unroll
  for (int i = 0; i < 4; ++i) {
    #pragma unroll
    for (int j = 0; j < 4; ++j) {
      const int gi = ib + tm + i;   // k-dim of qg GEMM
      const int gj = jb + tn + j;   // n-dim
      const float v = acc[i][j] * SCORE_SCALE;
      const unsigned short hi = f2bf(v);
      const unsigned short lo = f2bf(v - bf2f(hi));
      const int toff = t64_off(gj & 63, gi & 31);
      *(unsigned short*)((char*)Gt + ((size_t)((gi >> 5) * 8 + (gj >> 6)) << 12) + toff) = hi;
      *(unsigned short*)((char*)Gt + ((size_t)(((gi >> 5) + 16) * 8 + (gj >> 6)) << 12) + toff) = lo;
    }
  }
}

// ---------------- Wv/Wo -> T64 hi tiles (W^T layout) ----------------
__global__ __launch_bounds__(256) void wconv_kernel(
    const float* __restrict__ Wv, const float* __restrict__ Wo,
    unsigned short* __restrict__ Wvt, unsigned short* __restrict__ Wot)
{
  __shared__ char img[32768];
  const int ktile = blockIdx.x;  // 0..15
  const int mat   = blockIdx.y;  // 0:Wv 1:Wo
  const float* W = mat ? Wo : Wv;
  unsigned short* Dt = mat ? Wot : Wvt;
  const int tid = threadIdx.x;
  const int k  = tid >> 3;       // 0..31
  const int nt = tid & 7;        // ntile 0..7
  #pragma unroll
  for (int e4 = 0; e4 < 16; ++e4) {
    float4 w = *(const float4*)&W[(size_t)(ktile * 32 + k) * 512 + nt * 64 + e4 * 4];
    float vv[4] = {w.x, w.y, w.z, w.w};
    #pragma unroll
    for (int c = 0; c < 4; ++c) {
      const int n = e4 * 4 + c;
      *(unsigned short*)(img + nt * 4096 + t64_off(n, k)) = f2bf(vv[c]);
    }
  }
  __syncthreads();
  const uint4* src = (const uint4*)img;
  uint4* dst = (uint4*)((char*)Dt + (size_t)ktile * 32768);
  for (int i = tid; i < 2048; i += 256) dst[i] = src[i];
}

// ---------------- qg projection: qg = FiLM(query)@G + u  (split hi/lo, single K-pass) ----
// BM=64, BN=256, 256 thr (4 waves 2x2). Per k-step: stage Ah,Al,Bh,Bl; 48 MFMAs;
// 2-barrier epochs. 3-product compensated schedule: Ah*Bh + Al*Bh + Ah*Bl.
__global__ __launch_bounds__(256) void proj_split(
    const float* __restrict__ A, const unsigned short* __restrict__ Bt,
    const float* __restrict__ bias, const float* __restrict__ gb,
    float* __restrict__ Cf)
{
  __shared__ char smem[40960];   // LAh 4K | LAl 4K | LBh 16K | LBl 16K
  char* const LAh = smem;
  char* const LAl = smem + 4096;
  char* const LBh = smem + 8192;
  char* const LBl = smem + 24576;

  const int tid  = threadIdx.x;
  const int lane = tid & 63, l15 = lane & 15, g = lane >> 4;
  const int wave = tid >> 6, wm = wave >> 1, wn = wave & 1;
  const int mBlk = blockIdx.y;
  const int nBlk = blockIdx.x;

  const int sr = tid >> 2;   // 0..63
  const int sq = tid & 3;    // k-octet
  const size_t arow = (size_t)(mBlk * 64 + sr) * 512 + sq * 8;
  const int gbbase = ((mBlk >> 4) * 1024) + sq * 8;
  const int awoff = t64_off(sr, sq * 8);

  int aoff[2], boff[8];
  #pragma unroll
  for (int fm = 0; fm < 2; ++fm) aoff[fm] = frag_off(wm * 32 + fm * 16 + l15, g);
  #pragma unroll
  for (int fn = 0; fn < 8; ++fn) {
    const int n = wn * 128 + fn * 16 + l15;
    boff[fn] = ((n >> 6) << 12) + frag_off(n & 63, g);
  }

  v4f acc[2][8];
  #pragma unroll
  for (int fm = 0; fm < 2; ++fm)
    #pragma unroll
    for (int fn = 0; fn < 8; ++fn) acc[fm][fn] = (v4f){0.f, 0.f, 0.f, 0.f};

  for (int tk = 0; tk < 16; ++tk) {
    const int kd = tk * 32;
    {  // B hi + lo tiles (16 KB each), identity-copy via global_load_lds
      const char* gsh = (const char*)Bt + ((size_t)(tk * 8 + nBlk * 4) << 12) + (size_t)tid * 16;
      const char* gsl = (const char*)Bt + ((size_t)((tk + 16) * 8 + nBlk * 4) << 12) + (size_t)tid * 16;
      char* ldh = LBh + (wave << 10);
      char* ldl = LBl + (wave << 10);
      #pragma unroll
      for (int i = 0; i < 4; ++i) {
        gload_lds16(gsh + i * 4096, ldh + i * 4096);
        gload_lds16(gsl + i * 4096, ldl + i * 4096);
      }
    }
    {  // A: f32 -> (hi, lo) planes
      float4 x0 = *(const float4*)&A[arow + kd];
      float4 x1 = *(const float4*)&A[arow + kd + 4];
      float4 g0 = *(const float4*)&gb[gbbase + kd];
      float4 g1 = *(const float4*)&gb[gbbase + kd + 4];
      float4 b0 = *(const float4*)&gb[gbbase + 512 + kd];
      float4 b1 = *(const float4*)&gb[gbbase + 512 + kd + 4];
      x0.x = fmaf(x0.x, 1.f + g0.x, b0.x); x0.y = fmaf(x0.y, 1.f + g0.y, b0.y);
      x0.z = fmaf(x0.z, 1.f + g0.z, b0.z); x0.w = fmaf(x0.w, 1.f + g0.w, b0.w);
      x1.x = fmaf(x1.x, 1.f + g1.x, b1.x); x1.y = fmaf(x1.y, 1.f + g1.y, b1.y);
      x1.z = fmaf(x1.z, 1.f + g1.z, b1.z); x1.w = fmaf(x1.w, 1.f + g1.w, b1.w);
      uint4 hi4, lo4;
      cvt8pair(x0, x1, hi4, lo4);
      *(uint4*)(LAh + awoff) = hi4;
      *(uint4*)(LAl + awoff) = lo4;
    }
    __syncthreads();   // write-epoch -> read-epoch
    const v8s ah0 = *(const v8s*)(LAh + aoff[0]);
    const v8s ah1 = *(const v8s*)(LAh + aoff[1]);
    const v8s al0 = *(const v8s*)(LAl + aoff[0]);
    const v8s al1 = *(const v8s*)(LAl + aoff[1]);
    #pragma unroll
    for (int fn = 0; fn < 8; ++fn) {
      const v8s bh = *(const v8s*)(LBh + boff[fn]);
      const v8s bl = *(const v8s*)(LBl + boff[fn]);
      acc[0][fn] = __builtin_amdgcn_mfma_f32_16x16x32_bf16(ah0, bh, acc[0][fn], 0, 0, 0);
      acc[1][fn] = __builtin_amdgcn_mfma_f32_16x16x32_bf16(ah1, bh, acc[1][fn], 0, 0, 0);
      acc[0][fn] = __builtin_amdgcn_mfma_f32_16x16x32_bf16(al0, bh, acc[0][fn], 0, 0, 0);
      acc[1][fn] = __builtin_amdgcn_mfma_f32_16x16x32_bf16(al1, bh, acc[1][fn], 0, 0, 0);
      acc[0][fn] = __builtin_amdgcn_mfma_f32_16x16x32_bf16(ah0, bl, acc[0][fn], 0, 0, 0);
      acc[1][fn] = __builtin_amdgcn_mfma_f32_16x16x32_bf16(ah1, bl, acc[1][fn], 0, 0, 0);
    }
    __syncthreads();   // read-epoch -> next write-epoch
  }

  #pragma unroll
  for (int fn = 0; fn < 8; ++fn) {
    const int col = nBlk * 256 + wn * 128 + fn * 16 + l15;
    const float bv = bias[col];   // u (pre-scaled) folded as bias
    #pragma unroll
    for (int fm = 0; fm < 2; ++fm) {
      const int r0 = mBlk * 64 + wm * 32 + fm * 16 + g * 4;
      #pragma unroll
      for (int k = 0; k < 4; ++k)
        Cf[(size_t)(r0 + k) * 512 + col] = acc[fm][fn][k] + bv;
    }
  }
}

// ---------------- Simple projection: C[M,512] = A @ Bt + bias ----------------
// BM=64, BN=512, 512 thr (8 waves 2x4; wave tile 32x128), single bf16 product.
template<bool OUTBF16>
__global__ __launch_bounds__(512) void proj_simple(
    const float* __restrict__ A, const unsigned short* __restrict__ Bt,
    const float* __restrict__ bias, float* __restrict__ Cf,
    unsigned short* __restrict__ Cb)
{
  __shared__ char smem[4096 + 32768];   // LA 4K | LB 32K
  char* const LA = smem;
  char* const LB = smem + 4096;

  const int tid  = threadIdx.x;
  const int lane = tid & 63, l15 = lane & 15, g = lane >> 4;
  const int wave = tid >> 6, wm = wave >> 2, wn = wave & 3;
  const int mBlk = blockIdx.x;

  const int sr  = tid >> 3;   // 0..63
  const int sq4 = tid & 7;    // k-quad
  const size_t arow = (size_t)(mBlk * 64 + sr) * 512 + sq4 * 4;
  const int awoff = t64_off(sr, sq4 * 4);   // (k&7)==0 or 4 -> byte 0 or 8 within slot

  int aoff[2], boff[8];
  #pragma unroll
  for (int fm = 0; fm < 2; ++fm) aoff[fm] = frag_off(wm * 32 + fm * 16 + l15, g);
  #pragma unroll
  for (int fn = 0; fn < 8; ++fn) {
    const int n = wn * 128 + fn * 16 + l15;
    boff[fn] = ((n >> 6) << 12) + frag_off(n & 63, g);
  }

  v4f acc[2][8];
  #pragma unroll
  for (int fm = 0; fm < 2; ++fm)
    #pragma unroll
    for (int fn = 0; fn < 8; ++fn) acc[fm][fn] = (v4f){0.f, 0.f, 0.f, 0.f};

  for (int tk = 0; tk < 16; ++tk) {
    const int kd = tk * 32;
    {  // B: 32 KB contiguous image for this k-step
      const char* gs = (const char*)Bt + ((size_t)tk << 15) + (wave << 12) + (lane << 4);
      char* ld = LB + (wave << 12);
      #pragma unroll
      for (int i = 0; i < 4; ++i) gload_lds16(gs + (i << 10), ld + (i << 10));
    }
    {  // A: f32 -> bf16 hi
      float4 x = *(const float4*)&A[arow + kd];
      *(uint2*)(LA + awoff) = cvt4(x);
    }
    __syncthreads();   // write-epoch -> read-epoch
    const v8s a0 = *(const v8s*)(LA + aoff[0]);
    const v8s a1 = *(const v8s*)(LA + aoff[1]);
    #pragma unroll
    for (int fn = 0; fn < 8; ++fn) {
      const v8s bb = *(const v8s*)(LB + boff[fn]);
      acc[0][fn] = __builtin_amdgcn_mfma_f32_16x16x32_bf16(a0, bb, acc[0][fn], 0, 0, 0);
      acc[1][fn] = __builtin_amdgcn_mfma_f32_16x16x32_bf16(a1, bb, acc[1][fn], 0, 0, 0);
    }
    __syncthreads();   // read-epoch -> next write-epoch
  }

  #pragma unroll
  for (int fn = 0; fn < 8; ++fn) {
    const int col = wn * 128 + fn * 16 + l15;
    const float bv = bias[col];
    #pragma unroll
    for (int fm = 0; fm < 2; ++fm) {
      const int r0 = mBlk * 64 + wm * 32 + fm * 16 + g * 4;
      #pragma unroll
      for (int k = 0; k < 4; ++k) {
        const float v = acc[fm][fn][k] + bv;
        if (OUTBF16) Cb[(size_t)(r0 + k) * 512 + col] = f2bf(v);
        else         Cf[(size_t)(r0 + k) * 512 + col] = v;
      }
    }
  }
}

// ---------------- Windowed scores: S = qg' . src^T  (split hi/lo, single K-pass) ------
__global__ __launch_bounds__(256) void scores_mfma(
    const float* __restrict__ QG, const float* __restrict__ SRC,
    float* __restrict__ S)
{
  const int bs = blockIdx.y;
  const int s = bs & 15, b = bs >> 4;
  const int c  = CENTERS[s];
  const int lo = (c - 2 > 0) ? c - 2 : 0;
  const int hi = (c + 2 < 63) ? c + 2 : 63;
  if ((int)blockIdx.x > hi - lo) return;

  __shared__ char smem[16384];   // LAh | LAl | LBh | LBl (4K each)
  char* const LAh = smem;
  char* const LAl = smem + 4096;
  char* const LBh = smem + 8192;
  char* const LBl = smem + 12288;

  const int tid = threadIdx.x;
  const int lane = tid & 63, l15 = lane & 15, g = lane >> 4;
  const int wave = tid >> 6, wm = wave >> 1, wn = wave & 1;
  const int qbase  = bs << 6;
  const int kvrow0 = (b << 12) + ((lo + (int)blockIdx.x) << 6);
  const int sr = tid >> 2, sq = tid & 3;
  const size_t qrow = (size_t)(qbase + sr) * 512 + sq * 8;
  const size_t krow = (size_t)(kvrow0 + sr) * 512 + sq * 8;
  const int awoff = t64_off(sr, sq * 8);

  int aoff[2], boff[2];
  #pragma unroll
  for (int f = 0; f < 2; ++f) {
    aoff[f] = frag_off(wm * 32 + f * 16 + l15, g);
    boff[f] = frag_off(wn * 32 + f * 16 + l15, g);
  }

  v4f acc[2][2];
  #pragma unroll
  for (int i = 0; i < 2; ++i)
    #pragma unroll
    for (int j = 0; j < 2; ++j) acc[i][j] = (v4f){0.f, 0.f, 0.f, 0.f};

  for (int tk = 0; tk < 16; ++tk) {
    const int kd = tk * 32;
    {
      float4 x0 = *(const float4*)&QG[qrow + kd];
      float4 x1 = *(const float4*)&QG[qrow + kd + 4];
      uint4 ahi, alo;
      cvt8pair(x0, x1, ahi, alo);
      *(uint4*)(LAh + awoff) = ahi;
      *(uint4*)(LAl + awoff) = alo;
      float4 y0 = *(const float4*)&SRC[krow + kd];
      float4 y1 = *(const float4*)&SRC[krow + kd + 4];
      uint4 bhi, blo;
      cvt8pair(y0, y1, bhi, blo);
      *(uint4*)(LBh + awoff) = bhi;
      *(uint4*)(LBl + awoff) = blo;
    }
    __syncthreads();   // write-epoch -> read-epoch
    const v8s a0h = *(const v8s*)(LAh + aoff[0]);
    const v8s a1h = *(const v8s*)(LAh + aoff[1]);
    const v8s a0l = *(const v8s*)(LAl + aoff[0]);
    const v8s a1l = *(const v8s*)(LAl + aoff[1]);
    const v8s b0h = *(const v8s*)(LBh + boff[0]);
    const v8s b1h = *(const v8s*)(LBh + boff[1]);
    const v8s b0l = *(const v8s*)(LBl + boff[0]);
    const v8s b1l = *(const v8s*)(LBl + boff[1]);
    acc[0][0] = __builtin_amdgcn_mfma_f32_16x16x32_bf16(a0h, b0h, acc[0][0], 0, 0, 0);
    acc[0][1] = __builtin_amdgcn_mfma_f32_16x16x32_bf16(a0h, b1h, acc[0][1], 0, 0, 0);
    acc[1][0] = __builtin_amdgcn_mfma_f32_16x16x32_bf16(a1h, b0h, acc[1][0], 0, 0, 0);
    acc[1][1] = __builtin_amdgcn_mfma_f32_16x16x32_bf16(a1h, b1h, acc[1][1], 0, 0, 0);
    acc[0][0] = __builtin_amdgcn_mfma_f32_16x16x32_bf16(a0l, b0h, acc[0][0], 0, 0, 0);
    acc[0][1] = __builtin_amdgcn_mfma_f32_16x16x32_bf16(a0l, b1h, acc[0][1], 0, 0, 0);
    acc[1][0] = __builtin_amdgcn_mfma_f32_16x16x32_bf16(a1l, b0h, acc[1][0], 0, 0, 0);
    acc[1][1] = __builtin_amdgcn_mfma_f32_16x16x32_bf16(a1l, b1h, acc[1][1], 0, 0, 0);
    acc[0][0] = __builtin_amdgcn_mfma_f32_16x16x32_bf16(a0h, b0l, acc[0][0], 0, 0, 0);
    acc[0][1] = __builtin_amdgcn_mfma_f32_16x16x32_bf16(a0h, b1l, acc[0][1], 0, 0, 0);
    acc[1][0] = __builtin_amdgcn_mfma_f32_16x16x32_bf16(a1h, b0l, acc[1][0], 0, 0, 0);
    acc[1][1] = __builtin_amdgcn_mfma_f32_16x16x32_bf16(a1h, b1l, acc[1][1], 0, 0, 0);
    __syncthreads();   // read-epoch -> next write-epoch
  }

  #pragma unroll
  for (int fn = 0; fn < 2; ++fn) {
    const int cl = wn * 32 + fn * 16 + l15;
    const int colS = ((int)blockIdx.x << 6) + cl;
    #pragma unroll
    for (int fm = 0; fm < 2; ++fm) {
      const int r0 = qbase + wm * 32 + fm * 16 + g * 4;
      #pragma unroll
      for (int k = 0; k < 4; ++k)
        S[(size_t)(r0 + k) * NWIN + colS] = acc[fm][fn][k];
    }
  }
}

// ---------------- Top-32 + softmax + V gather (one wave per q-row) ----------------
__global__ __launch_bounds__(256) void topk_pv(
    const float* __restrict__ S, const unsigned short* __restrict__ Vb,
    float* __restrict__ O)
{
  const int lane = threadIdx.x & 63;
  const int wv   = threadIdx.x >> 6;
  const int row  = (blockIdx.x << 2) + wv;
  const int b    = row >> 10;
  const int s    = (row >> 6) & 15;
  const int c    = CENTERS[s];
  const int lo   = (c - 2 > 0) ? c - 2 : 0;
  const int hi   = (c + 2 < 63) ? c + 2 : 63;
  const int L    = (hi - lo + 1) << 6;
  const size_t vbase = ((size_t)b << 12) + ((size_t)lo << 6);

  const float* srow = S + (size_t)row * NWIN;
  float sc[5];
  #pragma unroll
  for (int j = 0; j < 5; ++j) {
    const int idx = lane + (j << 6);
    sc[j] = (idx < L) ? srow[idx] : -__builtin_inff();
  }

  float m = 0.f, denom = 0.f;
  float oacc[8] = {0.f,0.f,0.f,0.f,0.f,0.f,0.f,0.f};

  for (int t = 0; t < 32; ++t) {
    float val = sc[0]; int jl = 0;
    #pragma unroll
    for (int j = 1; j < 5; ++j)
      if (sc[j] > val) { val = sc[j]; jl = j; }
    int gi = lane + (jl << 6);
    #pragma unroll
    for (int off = 32; off > 0; off >>= 1) {
      float ov = __shfl_xor(val, off, 64);
      int   og = __shfl_xor(gi, off, 64);
      if (ov > val || (ov == val && og < gi)) { val = ov; gi = og; }
    }
    if (t == 0) m = val;
    const float p = __expf(val - m);
    denom += p;
    if ((gi & 63) == lane) {
      const int jw = gi >> 6;
      #pragma unroll
      for (int j = 0; j < 5; ++j)
        if (j == jw) sc[j] = -__builtin_inff();
    }
    const unsigned short* vrow = Vb + ((vbase + (size_t)gi) << 9);
    #pragma unroll
    for (int e = 0; e < 4; ++e) {
      unsigned raw = *(const unsigned*)&vrow[(lane << 1) + (e << 7)];
      oacc[2*e]     = fmaf(p, bflo(raw), oacc[2*e]);
      oacc[2*e + 1] = fmaf(p, bfhi(raw), oacc[2*e + 1]);
    }
  }

  const float inv = 1.0f / denom;
  float* orow = O + ((size_t)row << 9);
  #pragma unroll
  for (int e = 0; e < 4; ++e) {
    float2 o2 = make_float2(oacc[2*e] * inv, oacc[2*e + 1] * inv);
    *(float2*)&orow[(lane << 1) + (e << 7)] = o2;
  }
}

// ---------------------------------------------------------------------------------
extern "C" void kernel_launch(void* const* d_in, const int* in_sizes, int n_in,
                              void* d_out, int out_size, void* d_ws, size_t ws_size,
                              hipStream_t stream)
{
  (void)in_sizes; (void)n_in; (void)out_size; (void)ws_size;

  const float* query  = (const float*)d_in[0];
  const float* source = (const float*)d_in[1];
  const float* ctx1   = (const float*)d_in[2];
  const float* ctx2   = (const float*)d_in[3];
  const float* Wq     = (const float*)d_in[4];
  const float* bq     = (const float*)d_in[5];
  const float* Wk     = (const float*)d_in[6];
  // bk (d_in[7]) only contributes row-constant score terms -> provably droppable
  const float* Wv     = (const float*)d_in[8];
  const float* bv     = (const float*)d_in[9];
  const float* Wo     = (const float*)d_in[10];
  const float* bo     = (const float*)d_in[11];
  const float* Wc     = (const float*)d_in[12];
  const float* bc     = (const float*)d_in[13];
  float* out = (float*)d_out;

  // Workspace (~80.0 MB; round 1 proved >= 94.4 MB available):
  char* ws = (char*)d_ws;
  float*          qg   = (float*)(ws);                       // 16,777,216
  unsigned short* v    = (unsigned short*)(ws + 16777216);   // 33,554,432
  float*          S    = (float*)(ws + 50331648);            // 10,485,760
  float*          ctx  = (float*)(ws + 60817408);            // 16,777,216
  unsigned short* Gt   = (unsigned short*)(ws + 77594624);   //  1,048,576
  unsigned short* Wvt  = (unsigned short*)(ws + 78643200);   //    524,288
  unsigned short* Wot  = (unsigned short*)(ws + 79167488);   //    524,288
  float*          gb   = (float*)(ws + 79691776);            //     32,768
  float*          part = (float*)(ws + 79724544);            //    262,144
  float*          u    = (float*)(ws + 79986688);            //      2,048

  film_part  <<<dim3(8, 8), 1024, 0, stream>>>(ctx1, ctx2, Wc, part);
  film_reduce<<<8, 1024, 0, stream>>>(part, bc, gb);
  u_kernel   <<<512, 64, 0, stream>>>(Wk, bq, u);
  gmat_kernel<<<dim3(8, 8), 256, 0, stream>>>(Wq, Wk, Gt);
  wconv_kernel<<<dim3(16, 2), 256, 0, stream>>>(Wv, Wo, Wvt, Wot);

  // qg = FiLM(query) @ G_scaled + u_scaled   (split hi/lo, single K-pass)
  proj_split<<<dim3(2, 128), 256, 0, stream>>>(query, Gt, u, gb, qg);
  // v = source @ Wv + bv   (bf16 out, BN=512 so source is read once)
  proj_simple<true ><<<512, 512, 0, stream>>>(source, Wvt, bv, nullptr, v);
  // windowed scores (split hi/lo both operands, single K-pass; scale+bias pre-folded)
  scores_mfma<<<dim3(5, 128), 256, 0, stream>>>(qg, source, S);
  // top-32 + softmax + PV
  topk_pv<<<2048, 256, 0, stream>>>(S, v, ctx);
  // out = ctx @ Wo + bo
  proj_simple<false><<<128, 512, 0, stream>>>(ctx, Wot, bo, out, nullptr);
}

// Round 5
// 187.816 us; speedup vs baseline: 4.3001x; 1.1493x over previous
//
#include <hip/hip_runtime.h>

// LocalTopKCrossReadout: B=8, Lq=1024 (16 steps x 64), Lkv=4096 (64 x 64),
// DIM=512, WINDOW=2 (<=5 steps = 320 cols), TOPK=32.
#define NWIN 320
#define SCORE_SCALE 0.04419417382415922f  // 1/sqrt(512)

__constant__ int CENTERS[16] = {0,4,8,13,17,21,25,29,34,38,42,46,50,55,59,63};

typedef __attribute__((ext_vector_type(8))) short v8s;   // 8 bf16
typedef __attribute__((ext_vector_type(4))) float v4f;   // 4 f32 acc

__device__ __forceinline__ float bflo(unsigned u) { return __uint_as_float(u << 16); }
__device__ __forceinline__ float bfhi(unsigned u) { return __uint_as_float(u & 0xffff0000u); }
__device__ __forceinline__ float bf2f(unsigned short h) { return __uint_as_float(((unsigned)h) << 16); }
__device__ __forceinline__ unsigned short f2bf(float x) {
  unsigned u = __float_as_uint(x);
  unsigned r = 0x7fffu + ((u >> 16) & 1u);   // RNE
  return (unsigned short)((u + r) >> 16);
}

// ---- T64 tile: 64 rows x 32 k bf16 in 4096 B, XOR-swizzled for conflict-free b128 ----
__device__ __forceinline__ int t64_off(int r, int k) {
  return ((r & 31) << 7) + (((((r >> 5) << 2) | (k >> 3)) ^ (r & 7)) << 4) + ((k & 7) << 1);
}
__device__ __forceinline__ int frag_off(int r, int g) {
  return ((r & 31) << 7) + (((((r >> 5) << 2) | g) ^ (r & 7)) << 4);
}

__device__ __forceinline__ void gload_lds16(const void* g, void* l) {
  __builtin_amdgcn_global_load_lds((const __attribute__((address_space(1))) unsigned int*)g,
                                   (__attribute__((address_space(3))) unsigned int*)l, 16, 0, 0);
}

// pack 8 f32 -> hi-bf16 plane AND lo-residual plane in one shot
__device__ __forceinline__ void cvt8pair(float4 a, float4 b, uint4& hi4, uint4& lo4) {
  float v[8] = {a.x, a.y, a.z, a.w, b.x, b.y, b.z, b.w};
  unsigned short h[8], l[8];
  #pragma unroll
  for (int e = 0; e < 8; ++e) {
    h[e] = f2bf(v[e]);
    l[e] = f2bf(v[e] - bf2f(h[e]));
  }
  hi4.x = (unsigned)h[0] | ((unsigned)h[1] << 16);
  hi4.y = (unsigned)h[2] | ((unsigned)h[3] << 16);
  hi4.z = (unsigned)h[4] | ((unsigned)h[5] << 16);
  hi4.w = (unsigned)h[6] | ((unsigned)h[7] << 16);
  lo4.x = (unsigned)l[0] | ((unsigned)l[1] << 16);
  lo4.y = (unsigned)l[2] | ((unsigned)l[3] << 16);
  lo4.z = (unsigned)l[4] | ((unsigned)l[5] << 16);
  lo4.w = (unsigned)l[6] | ((unsigned)l[7] << 16);
}

__device__ __forceinline__ uint2 cvt4(float4 a) {
  uint2 r;
  r.x = (unsigned)f2bf(a.x) | ((unsigned)f2bf(a.y) << 16);
  r.y = (unsigned)f2bf(a.z) | ((unsigned)f2bf(a.w) << 16);
  return r;
}

// ---------------- FiLM (two-stage, parallel over k-slices) ----------------
__global__ void film_part(const float* __restrict__ ctx1, const float* __restrict__ ctx2,
                          const float* __restrict__ Wc, float* __restrict__ part)
{
  const int b = blockIdx.y, sl = blockIdx.x, j = threadIdx.x;
  const int i0 = sl * 128;
  float acc = 0.f;
  #pragma unroll 4
  for (int t = 0; t < 128; ++t) {
    const int i = i0 + t;
    const float f = (i < 512) ? ctx1[b * 512 + i] : ctx2[b * 512 + i - 512];
    acc = fmaf(f, Wc[(size_t)i * 1024 + j], acc);
  }
  part[(b * 8 + sl) * 1024 + j] = acc;
}

__global__ void film_reduce(const float* __restrict__ part, const float* __restrict__ bc,
                            float* __restrict__ gb)
{
  const int b = blockIdx.x, j = threadIdx.x;
  float acc = bc[j];
  #pragma unroll
  for (int sl = 0; sl < 8; ++sl) acc += part[(b * 8 + sl) * 1024 + j];
  gb[b * 1024 + j] = acc;
}

// ---------------- u = (Wk . bq) * scale  (512-dim) ----------------
__global__ void u_kernel(const float* __restrict__ Wk, const float* __restrict__ bq,
                         float* __restrict__ u)
{
  const int d = blockIdx.x, lane = threadIdx.x;
  float4 a0 = *(const float4*)&Wk[(size_t)d * 512 + lane * 8];
  float4 a1 = *(const float4*)&Wk[(size_t)d * 512 + lane * 8 + 4];
  float4 c0 = *(const float4*)&bq[lane * 8];
  float4 c1 = *(const float4*)&bq[lane * 8 + 4];
  float s = a0.x*c0.x + a0.y*c0.y + a0.z*c0.z + a0.w*c0.w
          + a1.x*c1.x + a1.y*c1.y + a1.z*c1.z + a1.w*c1.w;
  #pragma unroll
  for (int off = 32; off > 0; off >>= 1) s += __shfl_xor(s, off, 64);
  if (lane == 0) u[d] = s * SCORE_SCALE;
}

// ---------------- G = (Wq @ Wk^T)*scale (f32 exact) -> hi/lo T64 tiles ----------------
__global__ __launch_bounds__(256) void gmat_kernel(
    const float* __restrict__ Wq, const float* __restrict__ Wk,
    unsigned short* __restrict__ Gt)
{
  __shared__ float Qs[32][68];
  __shared__ float Ks[32][68];
  const int tid = threadIdx.x;
  const int ib = blockIdx.y << 6, jb = blockIdx.x << 6;
  const int tm = (tid >> 4) << 2, tn = (tid & 15) << 2;
  const int qr = tid >> 3, qk = (tid & 7) << 2;
  float acc[4][4] = {};
  for (int k0 = 0; k0 < 512; k0 += 32) {
    #pragma unroll
    for (int l = 0; l < 2; ++l) {
      const int r = qr + (l << 5);
      float4 a = *(const float4*)&Wq[(size_t)(ib + r) * 512 + k0 + qk];
      Qs[qk+0][r] = a.x; Qs[qk+1][r] = a.y; Qs[qk+2][r] = a.z; Qs[qk+3][r] = a.w;
      float4 w = *(const float4*)&Wk[(size_t)(jb + r) * 512 + k0 + qk];
      Ks[qk+0][r] = w.x; Ks[qk+1][r] = w.y; Ks[qk+2][r] = w.z; Ks[qk+3][r] = w.w;
    }
    __syncthreads();
    #pragma unroll 8
    for (int kk = 0; kk < 32; ++kk) {
      float a_[4], b_[4];
      *(float4*)&a_[0] = *(const float4*)&Qs[kk][tm];
      *(float4*)&b_[0] = *(const float4*)&Ks[kk][tn];
      #pragma unroll
      for (int i = 0; i < 4; ++i)
        #pragma unroll
        for (int j = 0; j < 4; ++j)
          acc[i][j] = fmaf(a_[i], b_[j], acc[i][j]);
    }
    __syncthreads();
  }
  #pragma unroll
  for (int i = 0; i < 4; ++i) {
    #pragma unroll
    for (int j = 0; j < 4; ++j) {
      const int gi = ib + tm + i;   // k-dim of qg GEMM
      const int gj = jb + tn + j;   // n-dim
      const float v = acc[i][j] * SCORE_SCALE;
      const unsigned short hi = f2bf(v);
      const unsigned short lo = f2bf(v - bf2f(hi));
      const int toff = t64_off(gj & 63, gi & 31);
      *(unsigned short*)((char*)Gt + ((size_t)((gi >> 5) * 8 + (gj >> 6)) << 12) + toff) = hi;
      *(unsigned short*)((char*)Gt + ((size_t)(((gi >> 5) + 16) * 8 + (gj >> 6)) << 12) + toff) = lo;
    }
  }
}

// ---------------- Wv/Wo -> T64 hi tiles (W^T layout) ----------------
__global__ __launch_bounds__(256) void wconv_kernel(
    const float* __restrict__ Wv, const float* __restrict__ Wo,
    unsigned short* __restrict__ Wvt, unsigned short* __restrict__ Wot)
{
  __shared__ char img[32768];
  const int ktile = blockIdx.x;  // 0..15
  const int mat   = blockIdx.y;  // 0:Wv 1:Wo
  const float* W = mat ? Wo : Wv;
  unsigned short* Dt = mat ? Wot : Wvt;
  const int tid = threadIdx.x;
  const int k  = tid >> 3;       // 0..31
  const int nt = tid & 7;        // ntile 0..7
  #pragma unroll
  for (int e4 = 0; e4 < 16; ++e4) {
    float4 w = *(const float4*)&W[(size_t)(ktile * 32 + k) * 512 + nt * 64 + e4 * 4];
    float vv[4] = {w.x, w.y, w.z, w.w};
    #pragma unroll
    for (int c = 0; c < 4; ++c) {
      const int n = e4 * 4 + c;
      *(unsigned short*)(img + nt * 4096 + t64_off(n, k)) = f2bf(vv[c]);
    }
  }
  __syncthreads();
  const uint4* src = (const uint4*)img;
  uint4* dst = (uint4*)((char*)Dt + (size_t)ktile * 32768);
  for (int i = tid; i < 2048; i += 256) dst[i] = src[i];
}

// ---------------- qg projection: qg = FiLM(query)@G + u  (split hi/lo, single K-pass) ----
__global__ __launch_bounds__(256) void proj_split(
    const float* __restrict__ A, const unsigned short* __restrict__ Bt,
    const float* __restrict__ bias, const float* __restrict__ gb,
    float* __restrict__ Cf)
{
  __shared__ char smem[40960];   // LAh 4K | LAl 4K | LBh 16K | LBl 16K
  char* const LAh = smem;
  char* const LAl = smem + 4096;
  char* const LBh = smem + 8192;
  char* const LBl = smem + 24576;

  const int tid  = threadIdx.x;
  const int lane = tid & 63, l15 = lane & 15, g = lane >> 4;
  const int wave = tid >> 6, wm = wave >> 1, wn = wave & 1;
  const int mBlk = blockIdx.y;
  const int nBlk = blockIdx.x;

  const int sr = tid >> 2;   // 0..63
  const int sq = tid & 3;    // k-octet
  const size_t arow = (size_t)(mBlk * 64 + sr) * 512 + sq * 8;
  const int gbbase = ((mBlk >> 4) * 1024) + sq * 8;
  const int awoff = t64_off(sr, sq * 8);

  int aoff[2], boff[8];
  #pragma unroll
  for (int fm = 0; fm < 2; ++fm) aoff[fm] = frag_off(wm * 32 + fm * 16 + l15, g);
  #pragma unroll
  for (int fn = 0; fn < 8; ++fn) {
    const int n = wn * 128 + fn * 16 + l15;
    boff[fn] = ((n >> 6) << 12) + frag_off(n & 63, g);
  }

  v4f acc[2][8];
  #pragma unroll
  for (int fm = 0; fm < 2; ++fm)
    #pragma unroll
    for (int fn = 0; fn < 8; ++fn) acc[fm][fn] = (v4f){0.f, 0.f, 0.f, 0.f};

  for (int tk = 0; tk < 16; ++tk) {
    const int kd = tk * 32;
    {  // B hi + lo tiles (16 KB each), identity-copy via global_load_lds
      const char* gsh = (const char*)Bt + ((size_t)(tk * 8 + nBlk * 4) << 12) + (size_t)tid * 16;
      const char* gsl = (const char*)Bt + ((size_t)((tk + 16) * 8 + nBlk * 4) << 12) + (size_t)tid * 16;
      char* ldh = LBh + (wave << 10);
      char* ldl = LBl + (wave << 10);
      #pragma unroll
      for (int i = 0; i < 4; ++i) {
        gload_lds16(gsh + i * 4096, ldh + i * 4096);
        gload_lds16(gsl + i * 4096, ldl + i * 4096);
      }
    }
    {  // A: f32 -> (hi, lo) planes
      float4 x0 = *(const float4*)&A[arow + kd];
      float4 x1 = *(const float4*)&A[arow + kd + 4];
      float4 g0 = *(const float4*)&gb[gbbase + kd];
      float4 g1 = *(const float4*)&gb[gbbase + kd + 4];
      float4 b0 = *(const float4*)&gb[gbbase + 512 + kd];
      float4 b1 = *(const float4*)&gb[gbbase + 512 + kd + 4];
      x0.x = fmaf(x0.x, 1.f + g0.x, b0.x); x0.y = fmaf(x0.y, 1.f + g0.y, b0.y);
      x0.z = fmaf(x0.z, 1.f + g0.z, b0.z); x0.w = fmaf(x0.w, 1.f + g0.w, b0.w);
      x1.x = fmaf(x1.x, 1.f + g1.x, b1.x); x1.y = fmaf(x1.y, 1.f + g1.y, b1.y);
      x1.z = fmaf(x1.z, 1.f + g1.z, b1.z); x1.w = fmaf(x1.w, 1.f + g1.w, b1.w);
      uint4 hi4, lo4;
      cvt8pair(x0, x1, hi4, lo4);
      *(uint4*)(LAh + awoff) = hi4;
      *(uint4*)(LAl + awoff) = lo4;
    }
    __syncthreads();   // write-epoch -> read-epoch
    const v8s ah0 = *(const v8s*)(LAh + aoff[0]);
    const v8s ah1 = *(const v8s*)(LAh + aoff[1]);
    const v8s al0 = *(const v8s*)(LAl + aoff[0]);
    const v8s al1 = *(const v8s*)(LAl + aoff[1]);
    #pragma unroll
    for (int fn = 0; fn < 8; ++fn) {
      const v8s bh = *(const v8s*)(LBh + boff[fn]);
      const v8s bl = *(const v8s*)(LBl + boff[fn]);
      acc[0][fn] = __builtin_amdgcn_mfma_f32_16x16x32_bf16(ah0, bh, acc[0][fn], 0, 0, 0);
      acc[1][fn] = __builtin_amdgcn_mfma_f32_16x16x32_bf16(ah1, bh, acc[1][fn], 0, 0, 0);
      acc[0][fn] = __builtin_amdgcn_mfma_f32_16x16x32_bf16(al0, bh, acc[0][fn], 0, 0, 0);
      acc[1][fn] = __builtin_amdgcn_mfma_f32_16x16x32_bf16(al1, bh, acc[1][fn], 0, 0, 0);
      acc[0][fn] = __builtin_amdgcn_mfma_f32_16x16x32_bf16(ah0, bl, acc[0][fn], 0, 0, 0);
      acc[1][fn] = __builtin_amdgcn_mfma_f32_16x16x32_bf16(ah1, bl, acc[1][fn], 0, 0, 0);
    }
    __syncthreads();   // read-epoch -> next write-epoch
  }

  #pragma unroll
  for (int fn = 0; fn < 8; ++fn) {
    const int col = nBlk * 256 + wn * 128 + fn * 16 + l15;
    const float bv = bias[col];   // u (pre-scaled) folded as bias
    #pragma unroll
    for (int fm = 0; fm < 2; ++fm) {
      const int r0 = mBlk * 64 + wm * 32 + fm * 16 + g * 4;
      #pragma unroll
      for (int k = 0; k < 4; ++k)
        Cf[(size_t)(r0 + k) * 512 + col] = acc[fm][fn][k] + bv;
    }
  }
}

// ---------------- Simple projection: C[M,512] = A @ Bt + bias ----------------
template<bool OUTBF16>
__global__ __launch_bounds__(512) void proj_simple(
    const float* __restrict__ A, const unsigned short* __restrict__ Bt,
    const float* __restrict__ bias, float* __restrict__ Cf,
    unsigned short* __restrict__ Cb)
{
  __shared__ char smem[4096 + 32768];   // LA 4K | LB 32K
  char* const LA = smem;
  char* const LB = smem + 4096;

  const int tid  = threadIdx.x;
  const int lane = tid & 63, l15 = lane & 15, g = lane >> 4;
  const int wave = tid >> 6, wm = wave >> 2, wn = wave & 3;
  const int mBlk = blockIdx.x;

  const int sr  = tid >> 3;   // 0..63
  const int sq4 = tid & 7;    // k-quad
  const size_t arow = (size_t)(mBlk * 64 + sr) * 512 + sq4 * 4;
  const int awoff = t64_off(sr, sq4 * 4);

  int aoff[2], boff[8];
  #pragma unroll
  for (int fm = 0; fm < 2; ++fm) aoff[fm] = frag_off(wm * 32 + fm * 16 + l15, g);
  #pragma unroll
  for (int fn = 0; fn < 8; ++fn) {
    const int n = wn * 128 + fn * 16 + l15;
    boff[fn] = ((n >> 6) << 12) + frag_off(n & 63, g);
  }

  v4f acc[2][8];
  #pragma unroll
  for (int fm = 0; fm < 2; ++fm)
    #pragma unroll
    for (int fn = 0; fn < 8; ++fn) acc[fm][fn] = (v4f){0.f, 0.f, 0.f, 0.f};

  for (int tk = 0; tk < 16; ++tk) {
    const int kd = tk * 32;
    {  // B: 32 KB contiguous image for this k-step
      const char* gs = (const char*)Bt + ((size_t)tk << 15) + (wave << 12) + (lane << 4);
      char* ld = LB + (wave << 12);
      #pragma unroll
      for (int i = 0; i < 4; ++i) gload_lds16(gs + (i << 10), ld + (i << 10));
    }
    {  // A: f32 -> bf16 hi
      float4 x = *(const float4*)&A[arow + kd];
      *(uint2*)(LA + awoff) = cvt4(x);
    }
    __syncthreads();   // write-epoch -> read-epoch
    const v8s a0 = *(const v8s*)(LA + aoff[0]);
    const v8s a1 = *(const v8s*)(LA + aoff[1]);
    #pragma unroll
    for (int fn = 0; fn < 8; ++fn) {
      const v8s bb = *(const v8s*)(LB + boff[fn]);
      acc[0][fn] = __builtin_amdgcn_mfma_f32_16x16x32_bf16(a0, bb, acc[0][fn], 0, 0, 0);
      acc[1][fn] = __builtin_amdgcn_mfma_f32_16x16x32_bf16(a1, bb, acc[1][fn], 0, 0, 0);
    }
    __syncthreads();   // read-epoch -> next write-epoch
  }

  #pragma unroll
  for (int fn = 0; fn < 8; ++fn) {
    const int col = wn * 128 + fn * 16 + l15;
    const float bv = bias[col];
    #pragma unroll
    for (int fm = 0; fm < 2; ++fm) {
      const int r0 = mBlk * 64 + wm * 32 + fm * 16 + g * 4;
      #pragma unroll
      for (int k = 0; k < 4; ++k) {
        const float v = acc[fm][fn][k] + bv;
        if (OUTBF16) Cb[(size_t)(r0 + k) * 512 + col] = f2bf(v);
        else         Cf[(size_t)(r0 + k) * 512 + col] = v;
      }
    }
  }
}

// ---------------- Windowed scores: S = qg' . src^T  (split hi/lo, single K-pass) ------
__global__ __launch_bounds__(256) void scores_mfma(
    const float* __restrict__ QG, const float* __restrict__ SRC,
    float* __restrict__ S)
{
  const int bs = blockIdx.y;
  const int s = bs & 15, b = bs >> 4;
  const int c  = CENTERS[s];
  const int lo = (c - 2 > 0) ? c - 2 : 0;
  const int hi = (c + 2 < 63) ? c + 2 : 63;
  if ((int)blockIdx.x > hi - lo) return;

  __shared__ char smem[16384];   // LAh | LAl | LBh | LBl (4K each)
  char* const LAh = smem;
  char* const LAl = smem + 4096;
  char* const LBh = smem + 8192;
  char* const LBl = smem + 12288;

  const int tid = threadIdx.x;
  const int lane = tid & 63, l15 = lane & 15, g = lane >> 4;
  const int wave = tid >> 6, wm = wave >> 1, wn = wave & 1;
  const int qbase  = bs << 6;
  const int kvrow0 = (b << 12) + ((lo + (int)blockIdx.x) << 6);
  const int sr = tid >> 2, sq = tid & 3;
  const size_t qrow = (size_t)(qbase + sr) * 512 + sq * 8;
  const size_t krow = (size_t)(kvrow0 + sr) * 512 + sq * 8;
  const int awoff = t64_off(sr, sq * 8);

  int aoff[2], boff[2];
  #pragma unroll
  for (int f = 0; f < 2; ++f) {
    aoff[f] = frag_off(wm * 32 + f * 16 + l15, g);
    boff[f] = frag_off(wn * 32 + f * 16 + l15, g);
  }

  v4f acc[2][2];
  #pragma unroll
  for (int i = 0; i < 2; ++i)
    #pragma unroll
    for (int j = 0; j < 2; ++j) acc[i][j] = (v4f){0.f, 0.f, 0.f, 0.f};

  for (int tk = 0; tk < 16; ++tk) {
    const int kd = tk * 32;
    {
      float4 x0 = *(const float4*)&QG[qrow + kd];
      float4 x1 = *(const float4*)&QG[qrow + kd + 4];
      uint4 ahi, alo;
      cvt8pair(x0, x1, ahi, alo);
      *(uint4*)(LAh + awoff) = ahi;
      *(uint4*)(LAl + awoff) = alo;
      float4 y0 = *(const float4*)&SRC[krow + kd];
      float4 y1 = *(const float4*)&SRC[krow + kd + 4];
      uint4 bhi, blo;
      cvt8pair(y0, y1, bhi, blo);
      *(uint4*)(LBh + awoff) = bhi;
      *(uint4*)(LBl + awoff) = blo;
    }
    __syncthreads();   // write-epoch -> read-epoch
    const v8s a0h = *(const v8s*)(LAh + aoff[0]);
    const v8s a1h = *(const v8s*)(LAh + aoff[1]);
    const v8s a0l = *(const v8s*)(LAl + aoff[0]);
    const v8s a1l = *(const v8s*)(LAl + aoff[1]);
    const v8s b0h = *(const v8s*)(LBh + boff[0]);
    const v8s b1h = *(const v8s*)(LBh + boff[1]);
    const v8s b0l = *(const v8s*)(LBl + boff[0]);
    const v8s b1l = *(const v8s*)(LBl + boff[1]);
    acc[0][0] = __builtin_amdgcn_mfma_f32_16x16x32_bf16(a0h, b0h, acc[0][0], 0, 0, 0);
    acc[0][1] = __builtin_amdgcn_mfma_f32_16x16x32_bf16(a0h, b1h, acc[0][1], 0, 0, 0);
    acc[1][0] = __builtin_amdgcn_mfma_f32_16x16x32_bf16(a1h, b0h, acc[1][0], 0, 0, 0);
    acc[1][1] = __builtin_amdgcn_mfma_f32_16x16x32_bf16(a1h, b1h, acc[1][1], 0, 0, 0);
    acc[0][0] = __builtin_amdgcn_mfma_f32_16x16x32_bf16(a0l, b0h, acc[0][0], 0, 0, 0);
    acc[0][1] = __builtin_amdgcn_mfma_f32_16x16x32_bf16(a0l, b1h, acc[0][1], 0, 0, 0);
    acc[1][0] = __builtin_amdgcn_mfma_f32_16x16x32_bf16(a1l, b0h, acc[1][0], 0, 0, 0);
    acc[1][1] = __builtin_amdgcn_mfma_f32_16x16x32_bf16(a1l, b1h, acc[1][1], 0, 0, 0);
    acc[0][0] = __builtin_amdgcn_mfma_f32_16x16x32_bf16(a0h, b0l, acc[0][0], 0, 0, 0);
    acc[0][1] = __builtin_amdgcn_mfma_f32_16x16x32_bf16(a0h, b1l, acc[0][1], 0, 0, 0);
    acc[1][0] = __builtin_amdgcn_mfma_f32_16x16x32_bf16(a1h, b0l, acc[1][0], 0, 0, 0);
    acc[1][1] = __builtin_amdgcn_mfma_f32_16x16x32_bf16(a1h, b1l, acc[1][1], 0, 0, 0);
    __syncthreads();   // read-epoch -> next write-epoch
  }

  #pragma unroll
  for (int fn = 0; fn < 2; ++fn) {
    const int cl = wn * 32 + fn * 16 + l15;
    const int colS = ((int)blockIdx.x << 6) + cl;
    #pragma unroll
    for (int fm = 0; fm < 2; ++fm) {
      const int r0 = qbase + wm * 32 + fm * 16 + g * 4;
      #pragma unroll
      for (int k = 0; k < 4; ++k)
        S[(size_t)(r0 + k) * NWIN + colS] = acc[fm][fn][k];
    }
  }
}

// ---------------- Top-32 + softmax + V gather: radix-select, no extraction loop ------
__global__ __launch_bounds__(256) void topk_pv(
    const float* __restrict__ S, const unsigned short* __restrict__ Vb,
    float* __restrict__ O)
{
  __shared__ int   sel_i[4][32];
  __shared__ float sel_p[4][32];

  const int lane = threadIdx.x & 63;
  const int wv   = threadIdx.x >> 6;
  // XCD-affine bijective remap: the 16 blocks of one step-group share b0&7 -> same XCD
  const int b0   = blockIdx.x;
  const int grp  = (b0 & 7) + ((b0 >> 7) << 3);    // 0..127
  const int blk  = (b0 >> 3) & 15;                 // 0..15
  const int row  = (((grp << 4) + blk) << 2) + wv; // 0..8191
  const int b    = row >> 10;
  const int s    = (row >> 6) & 15;
  const int c    = CENTERS[s];
  const int lo   = (c - 2 > 0) ? c - 2 : 0;
  const int hi   = (c + 2 < 63) ? c + 2 : 63;
  const int L    = (hi - lo + 1) << 6;
  const size_t vbase = ((size_t)b << 12) + ((size_t)lo << 6);

  const float* srow = S + (size_t)row * NWIN;
  float f[5]; unsigned uo[5];
  #pragma unroll
  for (int j = 0; j < 5; ++j) {
    const int idx = lane + (j << 6);
    const float v = (idx < L) ? srow[idx] : -__builtin_inff();
    f[j] = v;
    const unsigned fb = __float_as_uint(v);
    uo[j] = (fb & 0x80000000u) ? ~fb : (fb | 0x80000000u);  // order-preserving map
  }

  // row max (softmax shift)
  float m = f[0];
  #pragma unroll
  for (int j = 1; j < 5; ++j) m = fmaxf(m, f[j]);
  #pragma unroll
  for (int off = 32; off > 0; off >>= 1) m = fmaxf(m, __shfl_xor(m, off, 64));

  // T = exact 32nd-largest u (greedy MSB radix select; count via ballot+popc)
  unsigned T = 0u;
  for (int bit = 31; bit >= 0; --bit) {
    const unsigned cand = T | (1u << bit);
    int cnt = 0;
    #pragma unroll
    for (int j = 0; j < 5; ++j)
      cnt += __popcll(__ballot(uo[j] >= cand));
    if (cnt >= 32) T = cand;
  }

  // compaction: strict-greater first, then ==T by ascending index (matches lax.top_k)
  int base = 0;
  #pragma unroll
  for (int j = 0; j < 5; ++j) {
    const unsigned long long gm = __ballot(uo[j] > T);
    if (uo[j] > T) {
      const int rank = base + __builtin_amdgcn_mbcnt_hi(
          (unsigned)(gm >> 32), __builtin_amdgcn_mbcnt_lo((unsigned)gm, 0));
      sel_i[wv][rank] = lane + (j << 6);
      sel_p[wv][rank] = __expf(f[j] - m);
    }
    base += __popcll(gm);
  }
  #pragma unroll
  for (int j = 0; j < 5; ++j) {
    const unsigned long long em = __ballot(uo[j] == T);
    if (uo[j] == T) {
      const int er = base + __builtin_amdgcn_mbcnt_hi(
          (unsigned)(em >> 32), __builtin_amdgcn_mbcnt_lo((unsigned)em, 0));
      if (er < 32) {
        sel_i[wv][er] = lane + (j << 6);
        sel_p[wv][er] = __expf(f[j] - m);
      }
    }
    base += __popcll(em);
  }

  // same-wave LDS visibility (lockstep wave; no block barrier needed)
  asm volatile("s_waitcnt lgkmcnt(0)" ::: "memory");

  const int   si = sel_i[wv][lane & 31];
  const float sp = sel_p[wv][lane & 31];
  float dp = (lane < 32) ? sp : 0.f;
  #pragma unroll
  for (int off = 32; off > 0; off >>= 1) dp += __shfl_xor(dp, off, 64);

  float oacc[8] = {0.f,0.f,0.f,0.f,0.f,0.f,0.f,0.f};
  #pragma unroll
  for (int t = 0; t < 32; ++t) {
    const int   idx_t = __builtin_amdgcn_readlane(si, t);
    const float p_t   = __uint_as_float(
        (unsigned)__builtin_amdgcn_readlane((int)__float_as_uint(sp), t));
    const unsigned short* vrow = Vb + ((vbase + (size_t)idx_t) << 9);
    #pragma unroll
    for (int e = 0; e < 4; ++e) {
      const unsigned raw = *(const unsigned*)&vrow[(lane << 1) + (e << 7)];
      oacc[2*e]     = fmaf(p_t, bflo(raw), oacc[2*e]);
      oacc[2*e + 1] = fmaf(p_t, bfhi(raw), oacc[2*e + 1]);
    }
  }

  const float inv = 1.0f / dp;
  float* orow = O + ((size_t)row << 9);
  #pragma unroll
  for (int e = 0; e < 4; ++e) {
    float2 o2 = make_float2(oacc[2*e] * inv, oacc[2*e + 1] * inv);
    *(float2*)&orow[(lane << 1) + (e << 7)] = o2;
  }
}

// ---------------------------------------------------------------------------------
extern "C" void kernel_launch(void* const* d_in, const int* in_sizes, int n_in,
                              void* d_out, int out_size, void* d_ws, size_t ws_size,
                              hipStream_t stream)
{
  (void)in_sizes; (void)n_in; (void)out_size; (void)ws_size;

  const float* query  = (const float*)d_in[0];
  const float* source = (const float*)d_in[1];
  const float* ctx1   = (const float*)d_in[2];
  const float* ctx2   = (const float*)d_in[3];
  const float* Wq     = (const float*)d_in[4];
  const float* bq     = (const float*)d_in[5];
  const float* Wk     = (const float*)d_in[6];
  // bk (d_in[7]) only contributes row-constant score terms -> provably droppable
  const float* Wv     = (const float*)d_in[8];
  const float* bv     = (const float*)d_in[9];
  const float* Wo     = (const float*)d_in[10];
  const float* bo     = (const float*)d_in[11];
  const float* Wc     = (const float*)d_in[12];
  const float* bc     = (const float*)d_in[13];
  float* out = (float*)d_out;

  // Workspace (~80.0 MB; round 1 proved >= 94.4 MB available):
  char* ws = (char*)d_ws;
  float*          qg   = (float*)(ws);                       // 16,777,216
  unsigned short* v    = (unsigned short*)(ws + 16777216);   // 33,554,432
  float*          S    = (float*)(ws + 50331648);            // 10,485,760
  float*          ctx  = (float*)(ws + 60817408);            // 16,777,216
  unsigned short* Gt   = (unsigned short*)(ws + 77594624);   //  1,048,576
  unsigned short* Wvt  = (unsigned short*)(ws + 78643200);   //    524,288
  unsigned short* Wot  = (unsigned short*)(ws + 79167488);   //    524,288
  float*          gb   = (float*)(ws + 79691776);            //     32,768
  float*          part = (float*)(ws + 79724544);            //    262,144
  float*          u    = (float*)(ws + 79986688);            //      2,048

  film_part  <<<dim3(8, 8), 1024, 0, stream>>>(ctx1, ctx2, Wc, part);
  film_reduce<<<8, 1024, 0, stream>>>(part, bc, gb);
  u_kernel   <<<512, 64, 0, stream>>>(Wk, bq, u);
  gmat_kernel<<<dim3(8, 8), 256, 0, stream>>>(Wq, Wk, Gt);
  wconv_kernel<<<dim3(16, 2), 256, 0, stream>>>(Wv, Wo, Wvt, Wot);

  // qg = FiLM(query) @ G_scaled + u_scaled   (split hi/lo, single K-pass)
  proj_split<<<dim3(2, 128), 256, 0, stream>>>(query, Gt, u, gb, qg);
  // v = source @ Wv + bv   (bf16 out, BN=512 so source is read once)
  proj_simple<true ><<<512, 512, 0, stream>>>(source, Wvt, bv, nullptr, v);
  // windowed scores (split hi/lo both operands, single K-pass; scale+bias pre-folded)
  scores_mfma<<<dim3(5, 128), 256, 0, stream>>>(qg, source, S);
  // top-32 + softmax + PV  (radix-select)
  topk_pv<<<2048, 256, 0, stream>>>(S, v, ctx);
  // out = ctx @ Wo + bo
  proj_simple<false><<<128, 512, 0, stream>>>(ctx, Wot, bo, out, nullptr);
}

// Round 6
// 161.277 us; speedup vs baseline: 5.0077x; 1.1646x over previous
//
#include <hip/hip_runtime.h>

// LocalTopKCrossReadout: B=8, Lq=1024 (16 steps x 64), Lkv=4096 (64 x 64),
// DIM=512, WINDOW=2 (<=5 steps = 320 cols), TOPK=32.
#define NWIN 320
#define SCORE_SCALE 0.04419417382415922f  // 1/sqrt(512)

__constant__ int CENTERS[16] = {0,4,8,13,17,21,25,29,34,38,42,46,50,55,59,63};

typedef __attribute__((ext_vector_type(8))) short v8s;   // 8 bf16
typedef __attribute__((ext_vector_type(4))) float v4f;   // 4 f32 acc

__device__ __forceinline__ float bflo(unsigned u) { return __uint_as_float(u << 16); }
__device__ __forceinline__ float bfhi(unsigned u) { return __uint_as_float(u & 0xffff0000u); }
__device__ __forceinline__ float bf2f(unsigned short h) { return __uint_as_float(((unsigned)h) << 16); }
__device__ __forceinline__ unsigned short f2bf(float x) {
  unsigned u = __float_as_uint(x);
  unsigned r = 0x7fffu + ((u >> 16) & 1u);   // RNE
  return (unsigned short)((u + r) >> 16);
}

// ---- T64 tile: 64 rows x 32 k bf16 in 4096 B, XOR-swizzled for conflict-free b128 ----
__device__ __forceinline__ int t64_off(int r, int k) {
  return ((r & 31) << 7) + (((((r >> 5) << 2) | (k >> 3)) ^ (r & 7)) << 4) + ((k & 7) << 1);
}
__device__ __forceinline__ int frag_off(int r, int g) {
  return ((r & 31) << 7) + (((((r >> 5) << 2) | g) ^ (r & 7)) << 4);
}

__device__ __forceinline__ void gload_lds16(const void* g, void* l) {
  __builtin_amdgcn_global_load_lds((const __attribute__((address_space(1))) unsigned int*)g,
                                   (__attribute__((address_space(3))) unsigned int*)l, 16, 0, 0);
}

// pack 8 f32 -> hi-bf16 plane AND lo-residual plane in one shot
__device__ __forceinline__ void cvt8pair(float4 a, float4 b, uint4& hi4, uint4& lo4) {
  float v[8] = {a.x, a.y, a.z, a.w, b.x, b.y, b.z, b.w};
  unsigned short h[8], l[8];
  #pragma unroll
  for (int e = 0; e < 8; ++e) {
    h[e] = f2bf(v[e]);
    l[e] = f2bf(v[e] - bf2f(h[e]));
  }
  hi4.x = (unsigned)h[0] | ((unsigned)h[1] << 16);
  hi4.y = (unsigned)h[2] | ((unsigned)h[3] << 16);
  hi4.z = (unsigned)h[4] | ((unsigned)h[5] << 16);
  hi4.w = (unsigned)h[6] | ((unsigned)h[7] << 16);
  lo4.x = (unsigned)l[0] | ((unsigned)l[1] << 16);
  lo4.y = (unsigned)l[2] | ((unsigned)l[3] << 16);
  lo4.z = (unsigned)l[4] | ((unsigned)l[5] << 16);
  lo4.w = (unsigned)l[6] | ((unsigned)l[7] << 16);
}

__device__ __forceinline__ uint2 cvt4(float4 a) {
  uint2 r;
  r.x = (unsigned)f2bf(a.x) | ((unsigned)f2bf(a.y) << 16);
  r.y = (unsigned)f2bf(a.z) | ((unsigned)f2bf(a.w) << 16);
  return r;
}

// ---------------- FiLM (two-stage, parallel over k-slices) ----------------
__global__ void film_part(const float* __restrict__ ctx1, const float* __restrict__ ctx2,
                          const float* __restrict__ Wc, float* __restrict__ part)
{
  const int b = blockIdx.y, sl = blockIdx.x, j = threadIdx.x;
  const int i0 = sl * 128;
  float acc = 0.f;
  #pragma unroll 4
  for (int t = 0; t < 128; ++t) {
    const int i = i0 + t;
    const float f = (i < 512) ? ctx1[b * 512 + i] : ctx2[b * 512 + i - 512];
    acc = fmaf(f, Wc[(size_t)i * 1024 + j], acc);
  }
  part[(b * 8 + sl) * 1024 + j] = acc;
}

__global__ void film_reduce(const float* __restrict__ part, const float* __restrict__ bc,
                            float* __restrict__ gb)
{
  const int b = blockIdx.x, j = threadIdx.x;
  float acc = bc[j];
  #pragma unroll
  for (int sl = 0; sl < 8; ++sl) acc += part[(b * 8 + sl) * 1024 + j];
  gb[b * 1024 + j] = acc;
}

// ---------------- u = (Wk . bq) * scale  (512-dim) ----------------
__global__ void u_kernel(const float* __restrict__ Wk, const float* __restrict__ bq,
                         float* __restrict__ u)
{
  const int d = blockIdx.x, lane = threadIdx.x;
  float4 a0 = *(const float4*)&Wk[(size_t)d * 512 + lane * 8];
  float4 a1 = *(const float4*)&Wk[(size_t)d * 512 + lane * 8 + 4];
  float4 c0 = *(const float4*)&bq[lane * 8];
  float4 c1 = *(const float4*)&bq[lane * 8 + 4];
  float s = a0.x*c0.x + a0.y*c0.y + a0.z*c0.z + a0.w*c0.w
          + a1.x*c1.x + a1.y*c1.y + a1.z*c1.z + a1.w*c1.w;
  #pragma unroll
  for (int off = 32; off > 0; off >>= 1) s += __shfl_xor(s, off, 64);
  if (lane == 0) u[d] = s * SCORE_SCALE;
}

// ---------------- Wq/Wk -> row-major bf16 hi/lo planes ----------------
__global__ __launch_bounds__(256) void wsplit_kernel(
    const float* __restrict__ Wq, const float* __restrict__ Wk,
    unsigned short* __restrict__ Wqh, unsigned short* __restrict__ Wql,
    unsigned short* __restrict__ Wkh, unsigned short* __restrict__ Wkl)
{
  const int b = blockIdx.x;           // 0..255
  const int mat = b >> 7;             // 0: Wq, 1: Wk
  const float* Wsrc = mat ? Wk : Wq;
  unsigned short* Wh = mat ? Wkh : Wqh;
  unsigned short* Wl = mat ? Wkl : Wql;
  const size_t e0 = (((size_t)(b & 127) * 256) + threadIdx.x) * 8;
  float4 x0 = *(const float4*)&Wsrc[e0];
  float4 x1 = *(const float4*)&Wsrc[e0 + 4];
  uint4 h4, l4;
  cvt8pair(x0, x1, h4, l4);
  *(uint4*)&Wh[e0] = h4;
  *(uint4*)&Wl[e0] = l4;
}

// ---------------- G = (Wq @ Wk^T)*scale via split MFMA -> hi/lo T64 tiles ----------
// 1024 independent 16x16 wave-tiles; no LDS, no barriers; loads feed fragments
// directly. 3-product compensated schedule (Ah*Bh + Al*Bh + Ah*Bl).
__global__ __launch_bounds__(256) void gmat_mfma(
    const unsigned short* __restrict__ Wqh, const unsigned short* __restrict__ Wql,
    const unsigned short* __restrict__ Wkh, const unsigned short* __restrict__ Wkl,
    unsigned short* __restrict__ Gt)
{
  const int tid  = threadIdx.x;
  const int lane = tid & 63, l15 = lane & 15, g = lane >> 4;
  const int wave = tid >> 6;
  const int t  = ((int)blockIdx.x << 2) | wave;   // 0..1023
  const int ti = t >> 5, tj = t & 31;
  const int ib = ti << 4, jb = tj << 4;
  const size_t arow = (size_t)(ib + l15) * 512 + (g << 3);
  const size_t brow = (size_t)(jb + l15) * 512 + (g << 3);

  v4f acc = (v4f){0.f, 0.f, 0.f, 0.f};
  #pragma unroll 4
  for (int kk = 0; kk < 16; ++kk) {
    const int kd = kk * 32;
    const v8s ah = *(const v8s*)&Wqh[arow + kd];
    const v8s al = *(const v8s*)&Wql[arow + kd];
    const v8s bh = *(const v8s*)&Wkh[brow + kd];
    const v8s bl = *(const v8s*)&Wkl[brow + kd];
    acc = __builtin_amdgcn_mfma_f32_16x16x32_bf16(ah, bh, acc, 0, 0, 0);
    acc = __builtin_amdgcn_mfma_f32_16x16x32_bf16(al, bh, acc, 0, 0, 0);
    acc = __builtin_amdgcn_mfma_f32_16x16x32_bf16(ah, bl, acc, 0, 0, 0);
  }

  // C/D layout: col = lane&15 (gj), row = (lane>>4)*4 + k (gi)
  #pragma unroll
  for (int k = 0; k < 4; ++k) {
    const int gi = ib + (g << 2) + k;   // k-dim of qg GEMM
    const int gj = jb + l15;            // n-dim
    const float v = acc[k] * SCORE_SCALE;
    const unsigned short hi = f2bf(v);
    const unsigned short lo = f2bf(v - bf2f(hi));
    const int toff = t64_off(gj & 63, gi & 31);
    *(unsigned short*)((char*)Gt + ((size_t)((gi >> 5) * 8 + (gj >> 6)) << 12) + toff) = hi;
    *(unsigned short*)((char*)Gt + ((size_t)(((gi >> 5) + 16) * 8 + (gj >> 6)) << 12) + toff) = lo;
  }
}

// ---------------- Wv/Wo -> T64 hi tiles (W^T layout) ----------------
__global__ __launch_bounds__(256) void wconv_kernel(
    const float* __restrict__ Wv, const float* __restrict__ Wo,
    unsigned short* __restrict__ Wvt, unsigned short* __restrict__ Wot)
{
  __shared__ char img[32768];
  const int ktile = blockIdx.x;  // 0..15
  const int mat   = blockIdx.y;  // 0:Wv 1:Wo
  const float* W = mat ? Wo : Wv;
  unsigned short* Dt = mat ? Wot : Wvt;
  const int tid = threadIdx.x;
  const int k  = tid >> 3;       // 0..31
  const int nt = tid & 7;        // ntile 0..7
  #pragma unroll
  for (int e4 = 0; e4 < 16; ++e4) {
    float4 w = *(const float4*)&W[(size_t)(ktile * 32 + k) * 512 + nt * 64 + e4 * 4];
    float vv[4] = {w.x, w.y, w.z, w.w};
    #pragma unroll
    for (int c = 0; c < 4; ++c) {
      const int n = e4 * 4 + c;
      *(unsigned short*)(img + nt * 4096 + t64_off(n, k)) = f2bf(vv[c]);
    }
  }
  __syncthreads();
  const uint4* src = (const uint4*)img;
  uint4* dst = (uint4*)((char*)Dt + (size_t)ktile * 32768);
  for (int i = tid; i < 2048; i += 256) dst[i] = src[i];
}

// ---------------- qg projection: qg = FiLM(query)@G + u  (split hi/lo, single K-pass) ----
__global__ __launch_bounds__(256) void proj_split(
    const float* __restrict__ A, const unsigned short* __restrict__ Bt,
    const float* __restrict__ bias, const float* __restrict__ gb,
    float* __restrict__ Cf)
{
  __shared__ char smem[40960];   // LAh 4K | LAl 4K | LBh 16K | LBl 16K
  char* const LAh = smem;
  char* const LAl = smem + 4096;
  char* const LBh = smem + 8192;
  char* const LBl = smem + 24576;

  const int tid  = threadIdx.x;
  const int lane = tid & 63, l15 = lane & 15, g = lane >> 4;
  const int wave = tid >> 6, wm = wave >> 1, wn = wave & 1;
  const int mBlk = blockIdx.y;
  const int nBlk = blockIdx.x;

  const int sr = tid >> 2;   // 0..63
  const int sq = tid & 3;    // k-octet
  const size_t arow = (size_t)(mBlk * 64 + sr) * 512 + sq * 8;
  const int gbbase = ((mBlk >> 4) * 1024) + sq * 8;
  const int awoff = t64_off(sr, sq * 8);

  int aoff[2], boff[8];
  #pragma unroll
  for (int fm = 0; fm < 2; ++fm) aoff[fm] = frag_off(wm * 32 + fm * 16 + l15, g);
  #pragma unroll
  for (int fn = 0; fn < 8; ++fn) {
    const int n = wn * 128 + fn * 16 + l15;
    boff[fn] = ((n >> 6) << 12) + frag_off(n & 63, g);
  }

  v4f acc[2][8];
  #pragma unroll
  for (int fm = 0; fm < 2; ++fm)
    #pragma unroll
    for (int fn = 0; fn < 8; ++fn) acc[fm][fn] = (v4f){0.f, 0.f, 0.f, 0.f};

  for (int tk = 0; tk < 16; ++tk) {
    const int kd = tk * 32;
    {  // B hi + lo tiles (16 KB each), identity-copy via global_load_lds
      const char* gsh = (const char*)Bt + ((size_t)(tk * 8 + nBlk * 4) << 12) + (size_t)tid * 16;
      const char* gsl = (const char*)Bt + ((size_t)((tk + 16) * 8 + nBlk * 4) << 12) + (size_t)tid * 16;
      char* ldh = LBh + (wave << 10);
      char* ldl = LBl + (wave << 10);
      #pragma unroll
      for (int i = 0; i < 4; ++i) {
        gload_lds16(gsh + i * 4096, ldh + i * 4096);
        gload_lds16(gsl + i * 4096, ldl + i * 4096);
      }
    }
    {  // A: f32 -> (hi, lo) planes
      float4 x0 = *(const float4*)&A[arow + kd];
      float4 x1 = *(const float4*)&A[arow + kd + 4];
      float4 g0 = *(const float4*)&gb[gbbase + kd];
      float4 g1 = *(const float4*)&gb[gbbase + kd + 4];
      float4 b0 = *(const float4*)&gb[gbbase + 512 + kd];
      float4 b1 = *(const float4*)&gb[gbbase + 512 + kd + 4];
      x0.x = fmaf(x0.x, 1.f + g0.x, b0.x); x0.y = fmaf(x0.y, 1.f + g0.y, b0.y);
      x0.z = fmaf(x0.z, 1.f + g0.z, b0.z); x0.w = fmaf(x0.w, 1.f + g0.w, b0.w);
      x1.x = fmaf(x1.x, 1.f + g1.x, b1.x); x1.y = fmaf(x1.y, 1.f + g1.y, b1.y);
      x1.z = fmaf(x1.z, 1.f + g1.z, b1.z); x1.w = fmaf(x1.w, 1.f + g1.w, b1.w);
      uint4 hi4, lo4;
      cvt8pair(x0, x1, hi4, lo4);
      *(uint4*)(LAh + awoff) = hi4;
      *(uint4*)(LAl + awoff) = lo4;
    }
    __syncthreads();   // write-epoch -> read-epoch
    const v8s ah0 = *(const v8s*)(LAh + aoff[0]);
    const v8s ah1 = *(const v8s*)(LAh + aoff[1]);
    const v8s al0 = *(const v8s*)(LAl + aoff[0]);
    const v8s al1 = *(const v8s*)(LAl + aoff[1]);
    #pragma unroll
    for (int fn = 0; fn < 8; ++fn) {
      const v8s bh = *(const v8s*)(LBh + boff[fn]);
      const v8s bl = *(const v8s*)(LBl + boff[fn]);
      acc[0][fn] = __builtin_amdgcn_mfma_f32_16x16x32_bf16(ah0, bh, acc[0][fn], 0, 0, 0);
      acc[1][fn] = __builtin_amdgcn_mfma_f32_16x16x32_bf16(ah1, bh, acc[1][fn], 0, 0, 0);
      acc[0][fn] = __builtin_amdgcn_mfma_f32_16x16x32_bf16(al0, bh, acc[0][fn], 0, 0, 0);
      acc[1][fn] = __builtin_amdgcn_mfma_f32_16x16x32_bf16(al1, bh, acc[1][fn], 0, 0, 0);
      acc[0][fn] = __builtin_amdgcn_mfma_f32_16x16x32_bf16(ah0, bl, acc[0][fn], 0, 0, 0);
      acc[1][fn] = __builtin_amdgcn_mfma_f32_16x16x32_bf16(ah1, bl, acc[1][fn], 0, 0, 0);
    }
    __syncthreads();   // read-epoch -> next write-epoch
  }

  #pragma unroll
  for (int fn = 0; fn < 8; ++fn) {
    const int col = nBlk * 256 + wn * 128 + fn * 16 + l15;
    const float bv = bias[col];   // u (pre-scaled) folded as bias
    #pragma unroll
    for (int fm = 0; fm < 2; ++fm) {
      const int r0 = mBlk * 64 + wm * 32 + fm * 16 + g * 4;
      #pragma unroll
      for (int k = 0; k < 4; ++k)
        Cf[(size_t)(r0 + k) * 512 + col] = acc[fm][fn][k] + bv;
    }
  }
}

// ---------------- Simple projection: C[M,512] = A @ Bt + bias ----------------
template<bool OUTBF16>
__global__ __launch_bounds__(512) void proj_simple(
    const float* __restrict__ A, const unsigned short* __restrict__ Bt,
    const float* __restrict__ bias, float* __restrict__ Cf,
    unsigned short* __restrict__ Cb)
{
  __shared__ char smem[4096 + 32768];   // LA 4K | LB 32K
  char* const LA = smem;
  char* const LB = smem + 4096;

  const int tid  = threadIdx.x;
  const int lane = tid & 63, l15 = lane & 15, g = lane >> 4;
  const int wave = tid >> 6, wm = wave >> 2, wn = wave & 3;
  const int mBlk = blockIdx.x;

  const int sr  = tid >> 3;   // 0..63
  const int sq4 = tid & 7;    // k-quad
  const size_t arow = (size_t)(mBlk * 64 + sr) * 512 + sq4 * 4;
  const int awoff = t64_off(sr, sq4 * 4);

  int aoff[2], boff[8];
  #pragma unroll
  for (int fm = 0; fm < 2; ++fm) aoff[fm] = frag_off(wm * 32 + fm * 16 + l15, g);
  #pragma unroll
  for (int fn = 0; fn < 8; ++fn) {
    const int n = wn * 128 + fn * 16 + l15;
    boff[fn] = ((n >> 6) << 12) + frag_off(n & 63, g);
  }

  v4f acc[2][8];
  #pragma unroll
  for (int fm = 0; fm < 2; ++fm)
    #pragma unroll
    for (int fn = 0; fn < 8; ++fn) acc[fm][fn] = (v4f){0.f, 0.f, 0.f, 0.f};

  for (int tk = 0; tk < 16; ++tk) {
    const int kd = tk * 32;
    {  // B: 32 KB contiguous image for this k-step
      const char* gs = (const char*)Bt + ((size_t)tk << 15) + (wave << 12) + (lane << 4);
      char* ld = LB + (wave << 12);
      #pragma unroll
      for (int i = 0; i < 4; ++i) gload_lds16(gs + (i << 10), ld + (i << 10));
    }
    {  // A: f32 -> bf16 hi
      float4 x = *(const float4*)&A[arow + kd];
      *(uint2*)(LA + awoff) = cvt4(x);
    }
    __syncthreads();   // write-epoch -> read-epoch
    const v8s a0 = *(const v8s*)(LA + aoff[0]);
    const v8s a1 = *(const v8s*)(LA + aoff[1]);
    #pragma unroll
    for (int fn = 0; fn < 8; ++fn) {
      const v8s bb = *(const v8s*)(LB + boff[fn]);
      acc[0][fn] = __builtin_amdgcn_mfma_f32_16x16x32_bf16(a0, bb, acc[0][fn], 0, 0, 0);
      acc[1][fn] = __builtin_amdgcn_mfma_f32_16x16x32_bf16(a1, bb, acc[1][fn], 0, 0, 0);
    }
    __syncthreads();   // read-epoch -> next write-epoch
  }

  #pragma unroll
  for (int fn = 0; fn < 8; ++fn) {
    const int col = wn * 128 + fn * 16 + l15;
    const float bv = bias[col];
    #pragma unroll
    for (int fm = 0; fm < 2; ++fm) {
      const int r0 = mBlk * 64 + wm * 32 + fm * 16 + g * 4;
      #pragma unroll
      for (int k = 0; k < 4; ++k) {
        const float v = acc[fm][fn][k] + bv;
        if (OUTBF16) Cb[(size_t)(r0 + k) * 512 + col] = f2bf(v);
        else         Cf[(size_t)(r0 + k) * 512 + col] = v;
      }
    }
  }
}

// ---------------- Windowed scores: S = qg' . src^T  (split hi/lo, single K-pass) ------
__global__ __launch_bounds__(256) void scores_mfma(
    const float* __restrict__ QG, const float* __restrict__ SRC,
    float* __restrict__ S)
{
  const int bs = blockIdx.y;
  const int s = bs & 15, b = bs >> 4;
  const int c  = CENTERS[s];
  const int lo = (c - 2 > 0) ? c - 2 : 0;
  const int hi = (c + 2 < 63) ? c + 2 : 63;
  if ((int)blockIdx.x > hi - lo) return;

  __shared__ char smem[16384];   // LAh | LAl | LBh | LBl (4K each)
  char* const LAh = smem;
  char* const LAl = smem + 4096;
  char* const LBh = smem + 8192;
  char* const LBl = smem + 12288;

  const int tid = threadIdx.x;
  const int lane = tid & 63, l15 = lane & 15, g = lane >> 4;
  const int wave = tid >> 6, wm = wave >> 1, wn = wave & 1;
  const int qbase  = bs << 6;
  const int kvrow0 = (b << 12) + ((lo + (int)blockIdx.x) << 6);
  const int sr = tid >> 2, sq = tid & 3;
  const size_t qrow = (size_t)(qbase + sr) * 512 + sq * 8;
  const size_t krow = (size_t)(kvrow0 + sr) * 512 + sq * 8;
  const int awoff = t64_off(sr, sq * 8);

  int aoff[2], boff[2];
  #pragma unroll
  for (int f = 0; f < 2; ++f) {
    aoff[f] = frag_off(wm * 32 + f * 16 + l15, g);
    boff[f] = frag_off(wn * 32 + f * 16 + l15, g);
  }

  v4f acc[2][2];
  #pragma unroll
  for (int i = 0; i < 2; ++i)
    #pragma unroll
    for (int j = 0; j < 2; ++j) acc[i][j] = (v4f){0.f, 0.f, 0.f, 0.f};

  for (int tk = 0; tk < 16; ++tk) {
    const int kd = tk * 32;
    {
      float4 x0 = *(const float4*)&QG[qrow + kd];
      float4 x1 = *(const float4*)&QG[qrow + kd + 4];
      uint4 ahi, alo;
      cvt8pair(x0, x1, ahi, alo);
      *(uint4*)(LAh + awoff) = ahi;
      *(uint4*)(LAl + awoff) = alo;
      float4 y0 = *(const float4*)&SRC[krow + kd];
      float4 y1 = *(const float4*)&SRC[krow + kd + 4];
      uint4 bhi, blo;
      cvt8pair(y0, y1, bhi, blo);
      *(uint4*)(LBh + awoff) = bhi;
      *(uint4*)(LBl + awoff) = blo;
    }
    __syncthreads();   // write-epoch -> read-epoch
    const v8s a0h = *(const v8s*)(LAh + aoff[0]);
    const v8s a1h = *(const v8s*)(LAh + aoff[1]);
    const v8s a0l = *(const v8s*)(LAl + aoff[0]);
    const v8s a1l = *(const v8s*)(LAl + aoff[1]);
    const v8s b0h = *(const v8s*)(LBh + boff[0]);
    const v8s b1h = *(const v8s*)(LBh + boff[1]);
    const v8s b0l = *(const v8s*)(LBl + boff[0]);
    const v8s b1l = *(const v8s*)(LBl + boff[1]);
    acc[0][0] = __builtin_amdgcn_mfma_f32_16x16x32_bf16(a0h, b0h, acc[0][0], 0, 0, 0);
    acc[0][1] = __builtin_amdgcn_mfma_f32_16x16x32_bf16(a0h, b1h, acc[0][1], 0, 0, 0);
    acc[1][0] = __builtin_amdgcn_mfma_f32_16x16x32_bf16(a1h, b0h, acc[1][0], 0, 0, 0);
    acc[1][1] = __builtin_amdgcn_mfma_f32_16x16x32_bf16(a1h, b1h, acc[1][1], 0, 0, 0);
    acc[0][0] = __builtin_amdgcn_mfma_f32_16x16x32_bf16(a0l, b0h, acc[0][0], 0, 0, 0);
    acc[0][1] = __builtin_amdgcn_mfma_f32_16x16x32_bf16(a0l, b1h, acc[0][1], 0, 0, 0);
    acc[1][0] = __builtin_amdgcn_mfma_f32_16x16x32_bf16(a1l, b0h, acc[1][0], 0, 0, 0);
    acc[1][1] = __builtin_amdgcn_mfma_f32_16x16x32_bf16(a1l, b1h, acc[1][1], 0, 0, 0);
    acc[0][0] = __builtin_amdgcn_mfma_f32_16x16x32_bf16(a0h, b0l, acc[0][0], 0, 0, 0);
    acc[0][1] = __builtin_amdgcn_mfma_f32_16x16x32_bf16(a0h, b1l, acc[0][1], 0, 0, 0);
    acc[1][0] = __builtin_amdgcn_mfma_f32_16x16x32_bf16(a1h, b0l, acc[1][0], 0, 0, 0);
    acc[1][1] = __builtin_amdgcn_mfma_f32_16x16x32_bf16(a1h, b1l, acc[1][1], 0, 0, 0);
    __syncthreads();   // read-epoch -> next write-epoch
  }

  #pragma unroll
  for (int fn = 0; fn < 2; ++fn) {
    const int cl = wn * 32 + fn * 16 + l15;
    const int colS = ((int)blockIdx.x << 6) + cl;
    #pragma unroll
    for (int fm = 0; fm < 2; ++fm) {
      const int r0 = qbase + wm * 32 + fm * 16 + g * 4;
      #pragma unroll
      for (int k = 0; k < 4; ++k)
        S[(size_t)(r0 + k) * NWIN + colS] = acc[fm][fn][k];
    }
  }
}

// ---------------- Top-32 + softmax + V gather: radix-select, no extraction loop ------
__global__ __launch_bounds__(256) void topk_pv(
    const float* __restrict__ S, const unsigned short* __restrict__ Vb,
    float* __restrict__ O)
{
  __shared__ int   sel_i[4][32];
  __shared__ float sel_p[4][32];

  const int lane = threadIdx.x & 63;
  const int wv   = threadIdx.x >> 6;
  // XCD-affine bijective remap: the 16 blocks of one step-group share b0&7 -> same XCD
  const int b0   = blockIdx.x;
  const int grp  = (b0 & 7) + ((b0 >> 7) << 3);    // 0..127
  const int blk  = (b0 >> 3) & 15;                 // 0..15
  const int row  = (((grp << 4) + blk) << 2) + wv; // 0..8191
  const int b    = row >> 10;
  const int s    = (row >> 6) & 15;
  const int c    = CENTERS[s];
  const int lo   = (c - 2 > 0) ? c - 2 : 0;
  const int hi   = (c + 2 < 63) ? c + 2 : 63;
  const int L    = (hi - lo + 1) << 6;
  const size_t vbase = ((size_t)b << 12) + ((size_t)lo << 6);

  const float* srow = S + (size_t)row * NWIN;
  float f[5]; unsigned uo[5];
  #pragma unroll
  for (int j = 0; j < 5; ++j) {
    const int idx = lane + (j << 6);
    const float v = (idx < L) ? srow[idx] : -__builtin_inff();
    f[j] = v;
    const unsigned fb = __float_as_uint(v);
    uo[j] = (fb & 0x80000000u) ? ~fb : (fb | 0x80000000u);  // order-preserving map
  }

  // row max (softmax shift)
  float m = f[0];
  #pragma unroll
  for (int j = 1; j < 5; ++j) m = fmaxf(m, f[j]);
  #pragma unroll
  for (int off = 32; off > 0; off >>= 1) m = fmaxf(m, __shfl_xor(m, off, 64));

  // T = exact 32nd-largest u (greedy MSB radix select; count via ballot+popc)
  unsigned T = 0u;
  for (int bit = 31; bit >= 0; --bit) {
    const unsigned cand = T | (1u << bit);
    int cnt = 0;
    #pragma unroll
    for (int j = 0; j < 5; ++j)
      cnt += __popcll(__ballot(uo[j] >= cand));
    if (cnt >= 32) T = cand;
  }

  // compaction: strict-greater first, then ==T by ascending index (matches lax.top_k)
  int base = 0;
  #pragma unroll
  for (int j = 0; j < 5; ++j) {
    const unsigned long long gm = __ballot(uo[j] > T);
    if (uo[j] > T) {
      const int rank = base + __builtin_amdgcn_mbcnt_hi(
          (unsigned)(gm >> 32), __builtin_amdgcn_mbcnt_lo((unsigned)gm, 0));
      sel_i[wv][rank] = lane + (j << 6);
      sel_p[wv][rank] = __expf(f[j] - m);
    }
    base += __popcll(gm);
  }
  #pragma unroll
  for (int j = 0; j < 5; ++j) {
    const unsigned long long em = __ballot(uo[j] == T);
    if (uo[j] == T) {
      const int er = base + __builtin_amdgcn_mbcnt_hi(
          (unsigned)(em >> 32), __builtin_amdgcn_mbcnt_lo((unsigned)em, 0));
      if (er < 32) {
        sel_i[wv][er] = lane + (j << 6);
        sel_p[wv][er] = __expf(f[j] - m);
      }
    }
    base += __popcll(em);
  }

  // same-wave LDS visibility (lockstep wave; no block barrier needed)
  asm volatile("s_waitcnt lgkmcnt(0)" ::: "memory");

  const int   si = sel_i[wv][lane & 31];
  const float sp = sel_p[wv][lane & 31];
  float dp = (lane < 32) ? sp : 0.f;
  #pragma unroll
  for (int off = 32; off > 0; off >>= 1) dp += __shfl_xor(dp, off, 64);

  float oacc[8] = {0.f,0.f,0.f,0.f,0.f,0.f,0.f,0.f};
  #pragma unroll
  for (int t = 0; t < 32; ++t) {
    const int   idx_t = __builtin_amdgcn_readlane(si, t);
    const float p_t   = __uint_as_float(
        (unsigned)__builtin_amdgcn_readlane((int)__float_as_uint(sp), t));
    const unsigned short* vrow = Vb + ((vbase + (size_t)idx_t) << 9);
    #pragma unroll
    for (int e = 0; e < 4; ++e) {
      const unsigned raw = *(const unsigned*)&vrow[(lane << 1) + (e << 7)];
      oacc[2*e]     = fmaf(p_t, bflo(raw), oacc[2*e]);
      oacc[2*e + 1] = fmaf(p_t, bfhi(raw), oacc[2*e + 1]);
    }
  }

  const float inv = 1.0f / dp;
  float* orow = O + ((size_t)row << 9);
  #pragma unroll
  for (int e = 0; e < 4; ++e) {
    float2 o2 = make_float2(oacc[2*e] * inv, oacc[2*e + 1] * inv);
    *(float2*)&orow[(lane << 1) + (e << 7)] = o2;
  }
}

// ---------------------------------------------------------------------------------
extern "C" void kernel_launch(void* const* d_in, const int* in_sizes, int n_in,
                              void* d_out, int out_size, void* d_ws, size_t ws_size,
                              hipStream_t stream)
{
  (void)in_sizes; (void)n_in; (void)out_size; (void)ws_size;

  const float* query  = (const float*)d_in[0];
  const float* source = (const float*)d_in[1];
  const float* ctx1   = (const float*)d_in[2];
  const float* ctx2   = (const float*)d_in[3];
  const float* Wq     = (const float*)d_in[4];
  const float* bq     = (const float*)d_in[5];
  const float* Wk     = (const float*)d_in[6];
  // bk (d_in[7]) only contributes row-constant score terms -> provably droppable
  const float* Wv     = (const float*)d_in[8];
  const float* bv     = (const float*)d_in[9];
  const float* Wo     = (const float*)d_in[10];
  const float* bo     = (const float*)d_in[11];
  const float* Wc     = (const float*)d_in[12];
  const float* bc     = (const float*)d_in[13];
  float* out = (float*)d_out;

  // Workspace (~82.1 MB; round 1 proved >= 94.4 MB available):
  char* ws = (char*)d_ws;
  float*          qg   = (float*)(ws);                       // 16,777,216
  unsigned short* v    = (unsigned short*)(ws + 16777216);   // 33,554,432
  float*          S    = (float*)(ws + 50331648);            // 10,485,760
  float*          ctx  = (float*)(ws + 60817408);            // 16,777,216
  unsigned short* Gt   = (unsigned short*)(ws + 77594624);   //  1,048,576
  unsigned short* Wvt  = (unsigned short*)(ws + 78643200);   //    524,288
  unsigned short* Wot  = (unsigned short*)(ws + 79167488);   //    524,288
  float*          gb   = (float*)(ws + 79691776);            //     32,768
  float*          part = (float*)(ws + 79724544);            //    262,144
  float*          u    = (float*)(ws + 79986688);            //      2,048
  unsigned short* Wqh  = (unsigned short*)(ws + 79988736);   //    524,288
  unsigned short* Wql  = (unsigned short*)(ws + 80513024);   //    524,288
  unsigned short* Wkh  = (unsigned short*)(ws + 81037312);   //    524,288
  unsigned short* Wkl  = (unsigned short*)(ws + 81561600);   //    524,288

  film_part   <<<dim3(8, 8), 1024, 0, stream>>>(ctx1, ctx2, Wc, part);
  film_reduce <<<8, 1024, 0, stream>>>(part, bc, gb);
  u_kernel    <<<512, 64, 0, stream>>>(Wk, bq, u);
  wsplit_kernel<<<256, 256, 0, stream>>>(Wq, Wk, Wqh, Wql, Wkh, Wkl);
  gmat_mfma   <<<256, 256, 0, stream>>>(Wqh, Wql, Wkh, Wkl, Gt);
  wconv_kernel<<<dim3(16, 2), 256, 0, stream>>>(Wv, Wo, Wvt, Wot);

  // qg = FiLM(query) @ G_scaled + u_scaled   (split hi/lo, single K-pass)
  proj_split<<<dim3(2, 128), 256, 0, stream>>>(query, Gt, u, gb, qg);
  // v = source @ Wv + bv   (bf16 out, BN=512 so source is read once)
  proj_simple<true ><<<512, 512, 0, stream>>>(source, Wvt, bv, nullptr, v);
  // windowed scores (split hi/lo both operands, single K-pass; scale+bias pre-folded)
  scores_mfma<<<dim3(5, 128), 256, 0, stream>>>(qg, source, S);
  // top-32 + softmax + PV  (radix-select)
  topk_pv<<<2048, 256, 0, stream>>>(S, v, ctx);
  // out = ctx @ Wo + bo
  proj_simple<false><<<128, 512, 0, stream>>>(ctx, Wot, bo, out, nullptr);
}